// Round 8
// baseline (214.957 us; speedup 1.0000x reference)
//
#include <hip/hip_runtime.h>
#include <hip/hip_bf16.h>

#define B_    64
#define T_    256
#define K_    256
#define L_    51
#define LL_   2601
#define RS_   64      // row stride inside one tile
#define NG_   3328    // GEMM N: 52*64 (j rows 0..51; row 51 zero)
#define PSTP_ 3328    // P tile stride per (b,t): 52 rows * 64 (pad rows dropped)
#define PSTQ_ 4096    // Q tile stride per quad group: 64 rows * 64
#define MT_   128
#define NT_   128
#define LOG2E_ 1.4426950408889634f
#define LN2_  0.6931471805599453f

typedef __bf16 bf16x8 __attribute__((ext_vector_type(8)));
typedef float  f32x4  __attribute__((ext_vector_type(4)));
typedef unsigned int u32x4 __attribute__((ext_vector_type(4)));
typedef u32x4 __attribute__((may_alias)) u32x4_a;
typedef unsigned long long ull;
typedef ull __attribute__((may_alias)) ull_a;
typedef unsigned short ushort_a __attribute__((may_alias));

static __device__ __forceinline__ bf16x8 as_bf16x8(u32x4 u) {
    return __builtin_bit_cast(bf16x8, u);
}
static __device__ __forceinline__ unsigned short bf16bits(float x) {
    return __builtin_bit_cast(unsigned short, __float2bfloat16(x));
}
static __device__ __forceinline__ ull pack4(f32x4 a) {
    return (ull)bf16bits(a[0]) | ((ull)bf16bits(a[1]) << 16) |
           ((ull)bf16bits(a[2]) << 32) | ((ull)bf16bits(a[3]) << 48);
}
static __device__ __forceinline__ void gld_lds16(const void* g, void* l) {
    __builtin_amdgcn_global_load_lds(
        (const __attribute__((address_space(1))) unsigned int*)g,
        (__attribute__((address_space(3))) unsigned int*)l, 16, 0, 0);
}

#define DPP_STEP(v, OP, CTRL)                                                   \
    {                                                                           \
        int _x = __builtin_bit_cast(int, v);                                    \
        float _o = __builtin_bit_cast(                                          \
            float, __builtin_amdgcn_update_dpp(_x, _x, CTRL, 0xF, 0xF, true));  \
        v = OP(v, _o);                                                          \
    }
static __device__ __forceinline__ float addf(float a, float b) { return a + b; }

// ---------------------------------------------------------------------------
// prep_all: blk [0,64)   -> Wt rows n=j*64+i for i=blk (LDS transpose) + bias,
//                           both pre-scaled by log2(e) (epilogue uses exp2)
//           blk [64,1088)-> x fp32 -> bf16
// ---------------------------------------------------------------------------
__global__ __launch_bounds__(256) void prep_all(
    const float* __restrict__ trans_W, const float* __restrict__ trans_b,
    const float* __restrict__ state_W, const float* __restrict__ state_b,
    const float* __restrict__ x,
    __hip_bfloat16* __restrict__ Wt, float* __restrict__ bias,
    __hip_bfloat16* __restrict__ xb)
{
    __shared__ __align__(16) __hip_bfloat16 Wl[52 * 258];
    const int blk = blockIdx.x, tid = threadIdx.x;

    if (blk < 64) {
        const int i = blk;
        if (i < L_) {
            const int jp = tid & 63, kk = tid >> 6;
            if (jp < 52) {
                for (int k = kk; k < K_; k += 4) {
                    float v = 0.f;
                    if (jp < L_) v = (trans_W[(size_t)k * LL_ + i * L_ + jp] +
                                      state_W[k * L_ + jp]) * LOG2E_;
                    Wl[jp * 258 + k] = __float2bfloat16(v);
                }
            }
            __syncthreads();
            for (int idx = tid; idx < 52 * 32; idx += 256) {
                const int j = idx >> 5, c = idx & 31;
                const unsigned int* row = (const unsigned int*)&Wl[j * 258];
                u32x4 v;
                v[0] = row[c * 4 + 0]; v[1] = row[c * 4 + 1];
                v[2] = row[c * 4 + 2]; v[3] = row[c * 4 + 3];
                *(u32x4*)(Wt + (size_t)((j << 6) + i) * K_ + c * 8) = v;
            }
        } else {
            const u32x4 z = {};
            for (int idx = tid; idx < 52 * 32; idx += 256) {
                const int j = idx >> 5, c = idx & 31;
                *(u32x4*)(Wt + (size_t)((j << 6) + i) * K_ + c * 8) = z;
            }
        }
        if (tid < 52) {
            const int j = tid;
            bias[(j << 6) + i] =
                (i < L_ && j < L_) ? (trans_b[i * L_ + j] + state_b[j]) * LOG2E_
                                   : 0.f;
        }
    } else {
        const int n4 = B_ * T_ * K_ / 4;
        const float4* x4 = (const float4*)x;
        ushort4* xb4 = (ushort4*)xb;
        for (int idx = (blk - 64) * 256 + tid; idx < n4; idx += 1024 * 256) {
            float4 v = x4[idx];
            ushort4 o;
            o.x = bf16bits(v.x); o.y = bf16bits(v.y);
            o.z = bf16bits(v.z); o.w = bf16bits(v.w);
            xb4[idx] = o;
        }
    }
}

// ---------------------------------------------------------------------------
// GEMM + exp epilogue.  Round-5 interior verbatim.  Launched as 4 m-quarter
// dispatches (ytOff = quarter * mtiles/4) purely to (a) expose sub-55µs
// dispatches in the profile top-5 and (b) measure the per-dispatch gap via
// total-time delta.  Work per block is unchanged.
// ---------------------------------------------------------------------------
__global__ __launch_bounds__(256) void gemm_energy(
    const __hip_bfloat16* __restrict__ xb,   // [B*T][K]
    const __hip_bfloat16* __restrict__ Wt,   // [NG][K]
    const float* __restrict__ bias,          // [NG] (pre-scaled by log2e)
    const float* __restrict__ mask,          // [B][T]
    __hip_bfloat16* __restrict__ P,          // [B*Tc][PSTP]
    int t0, int Tc, int TcShift, int swz, int ytOff)
{
    __shared__ __align__(16) char smem[32768];   // A dbuf 16K | B dbuf 16K

    const int tid  = threadIdx.x;
    const int lane = tid & 63;
    const int wv   = tid >> 6;
    const int quad = lane >> 4;
    const int l16  = lane & 15;

    int xt, yt;
    if (swz) {                       // id%8 -> XCD; m-tile yt == id (mod 8)
        const int r8 = blockIdx.x & 7;
        const int h  = blockIdx.x >> 3;
        const int qd = h / 26;
        xt = h - qd * 26;
        yt = r8 + 8 * qd;
    } else {
        const int qd = blockIdx.x / 26;
        xt = blockIdx.x - qd * 26;
        yt = qd;
    }
    const int m0 = (ytOff + yt) * MT_;
    const int n0 = xt * NT_;
    const int mrow0 = (wv >> 1) * 64;
    const int ncol0 = (wv & 1) * 64;

    // early loads (issued before any staging so counted vmcnt stays valid)
    float bv[4];
#pragma unroll
    for (int nf = 0; nf < 4; ++nf) bv[nf] = bias[n0 + ncol0 + nf * 16 + l16];
    const int mrowg = m0 + mrow0 + lane;     // this lane's mask row
    const float mlane =
        mask[(mrowg >> TcShift) * T_ + t0 + (mrowg & (Tc - 1))];

    // staging: slot s=it*256+tid -> line=s>>3, phys=s&7; logical h=phys^(line&7)
    // -> tile row r=line*2+(h>>2), k-chunk c=h&3.  LDS dest stays linear.
    const char* asrc[2]; const char* bsrc[2]; char* adst[2]; char* bdst[2];
#pragma unroll
    for (int it = 0; it < 2; ++it) {
        const int s = it * 256 + tid;
        const int line = s >> 3, phys = s & 7;
        const int h = phys ^ (line & 7);
        const int r = line * 2 + (h >> 2);
        const int c = h & 3;
        const int ma = m0 + r;
        const int rg = (ma >> TcShift) * T_ + t0 + (ma & (Tc - 1));
        asrc[it] = (const char*)xb + (size_t)rg * 512 + c * 16;
        bsrc[it] = (const char*)Wt + (size_t)(n0 + r) * 512 + c * 16;
        adst[it] = smem + it * 4096 + wv * 1024;
        bdst[it] = smem + 16384 + it * 4096 + wv * 1024;
    }
    auto stage = [&](int kp, int bsel) {
        const int ko = kp * 64;
#pragma unroll
        for (int it = 0; it < 2; ++it) {
            gld_lds16(asrc[it] + ko, adst[it] + bsel * 8192);
            gld_lds16(bsrc[it] + ko, bdst[it] + bsel * 8192);
        }
    };

    stage(0, 0);

    f32x4 acc[4][4];                             // C-init = bias (scaled)
#pragma unroll
    for (int mf = 0; mf < 4; ++mf)
#pragma unroll
        for (int nf = 0; nf < 4; ++nf)
            acc[mf][nf] = (f32x4){bv[nf], bv[nf], bv[nf], bv[nf]};

#pragma unroll
    for (int kp = 0; kp < 8; ++kp) {
        if (kp < 7) {
            stage(kp + 1, (kp + 1) & 1);         // next phase, other buffer
            asm volatile("s_waitcnt vmcnt(4)" ::: "memory");  // phase kp done
        } else {
            asm volatile("s_waitcnt vmcnt(0)" ::: "memory");
        }
        __builtin_amdgcn_s_barrier();
        const u32x4_a* Av = (const u32x4_a*)(smem + (kp & 1) * 8192);
        const u32x4_a* Bv = (const u32x4_a*)(smem + 16384 + (kp & 1) * 8192);
        __builtin_amdgcn_s_setprio(1);
        bf16x8 af[4], bfr[4];
#pragma unroll
        for (int f = 0; f < 4; ++f) {
            const int ra = mrow0 + f * 16 + l16;
            const int ia = (ra >> 1) * 8 + ((((ra & 1) << 2) | quad) ^ ((ra >> 1) & 7));
            af[f]  = as_bf16x8(Av[ia]);
            const int rb = ncol0 + f * 16 + l16;
            const int ib = (rb >> 1) * 8 + ((((rb & 1) << 2) | quad) ^ ((rb >> 1) & 7));
            bfr[f] = as_bf16x8(Bv[ib]);
        }
#pragma unroll
        for (int mf = 0; mf < 4; ++mf)
#pragma unroll
            for (int nf = 0; nf < 4; ++nf)
                acc[mf][nf] = __builtin_amdgcn_mfma_f32_16x16x32_bf16(
                    af[mf], bfr[nf], acc[mf][nf], 0, 0, 0);
        __builtin_amdgcn_s_setprio(0);
        asm volatile("s_waitcnt lgkmcnt(0)" ::: "memory");  // reads landed
        if (kp < 7) __builtin_amdgcn_s_barrier();  // buffer safe to overwrite
    }
    __syncthreads();   // full fence before reusing smem as epilogue tile

    // ---- epilogue ----  E: 128 rows x 256 B, row ml rotated by 8*ml bytes
    char* E = smem;
    const int jcol = (n0 + ncol0) >> 6;          // wave-uniform tile row j
    const bool jok = jcol < L_;
    const bool fastw = __all(mlane == 1.f);      // wave-uniform unmasked path
    const int colb0 = (ncol0 + l16) * 2;

    if (!jok) {
#pragma unroll
        for (int mf = 0; mf < 4; ++mf)
#pragma unroll
            for (int r = 0; r < 4; ++r) {
                const int ml = mrow0 + mf * 16 + quad * 4 + r;
                char* erow = E + ml * 256;
                const int rot = (ml * 8) & 255;
#pragma unroll
                for (int nf = 0; nf < 4; ++nf)
                    *(ushort_a*)(erow + ((colb0 + nf * 32 + rot) & 255)) = 0;
            }
    } else if (fastw) {
        const bool ok3 = (l16 < 3);              // cols 48..50 valid at nf=3
#pragma unroll
        for (int mf = 0; mf < 4; ++mf)
#pragma unroll
            for (int r = 0; r < 4; ++r) {
                const int ml = mrow0 + mf * 16 + quad * 4 + r;
                char* erow = E + ml * 256;
                const int rot = (ml * 8) & 255;
#pragma unroll
                for (int nf = 0; nf < 4; ++nf) {
                    float v = __builtin_exp2f(acc[mf][nf][r]);
                    if (nf == 3) v = ok3 ? v : 0.f;
                    *(ushort_a*)(erow + ((colb0 + nf * 32 + rot) & 255)) =
                        bf16bits(v);
                }
            }
    } else {
#pragma unroll
        for (int mf = 0; mf < 4; ++mf)
#pragma unroll
            for (int r = 0; r < 4; ++r) {
                const int ml = mrow0 + mf * 16 + quad * 4 + r;
                const int t  = t0 + ((m0 + ml) & (Tc - 1));
                const float mval = __shfl(mlane, ml - mrow0);
                const bool idm = (mval == 0.f) && (t != 0);
                char* erow = E + ml * 256;
                const int rot = (ml * 8) & 255;
#pragma unroll
                for (int nf = 0; nf < 4; ++nf) {
                    const bool okn = (nf < 3) || (l16 < 3);
                    const int ii = nf * 16 + l16;
                    float v;
                    if (idm) v = (okn && ii == jcol) ? 1.f : 0.f;
                    else     v = okn ? __builtin_exp2f(acc[mf][nf][r] * mval) : 0.f;
                    *(ushort_a*)(erow + ((colb0 + nf * 32 + rot) & 255)) =
                        bf16bits(v);
                }
            }
    }
    __syncthreads();

    // Coalesced store: 16 lanes cover one row's 256 B contiguous
#pragma unroll
    for (int it2 = 0; it2 < 8; ++it2) {
        const int idx = it2 * 256 + tid;
        const int ml = idx >> 4, c = idx & 15;
        const char* erow = E + ml * 256;
        const int rot = (ml * 8) & 255;
        const ull lo = *(const ull_a*)(erow + ((c * 16 + rot) & 255));
        const ull hi = *(const ull_a*)(erow + ((c * 16 + 8 + rot) & 255));
        u32x4 v;
        v[0] = (unsigned int)lo; v[1] = (unsigned int)(lo >> 32);
        v[2] = (unsigned int)hi; v[3] = (unsigned int)(hi >> 32);
        *(u32x4*)(P + (size_t)(m0 + ml) * PSTP_ + n0 + c * 8) = v;
    }
}

// ---------------------------------------------------------------------------
// prod_quad: Q = T4·T3·T2·T1, all-MFMA pair tree.  Round-7 version verbatim
// (52-row LDS tiles, 39.9 KB, 4 blocks/CU; validated absmax 0).
// ---------------------------------------------------------------------------
__global__ __launch_bounds__(256) void prod_quad(
    const __hip_bfloat16* __restrict__ P,   // [B*Tc][PSTP]
    __hip_bfloat16* __restrict__ Q,         // [B*(Tc/4)][PSTQ]
    int Tc)
{
    __shared__ u32x4 Sm[4][416];                            // 4 x 52 rows = 26.6 KB
    __shared__ __align__(16) unsigned short Tb[2][52 * 64]; // 13.3 KB

    unsigned short* W2t = (unsigned short*)&Sm[0][0];       // 52-row overlay
    unsigned short* W4b = (unsigned short*)&Sm[2][0];

    const int tid  = threadIdx.x;
    const int wv   = tid >> 6;
    const int lane = tid & 63;
    const int quad = lane >> 4;
    const int l16  = lane & 15;
    const int bq = blockIdx.x;
    const int Tq = Tc >> 2;
    const int b  = bq / Tq;
    const int tq = bq - b * Tq;
    const __hip_bfloat16* tile0 = P + (size_t)(b * Tc + tq * 4) * PSTP_;

    // stage rows 0..51: wave wv owns tile wv, 7 parts (part 6 half-masked)
#pragma unroll
    for (int part = 0; part < 7; ++part) {
        const int slot = part * 64 + lane;
        const int r    = slot >> 3;
        if (r < 52) {
            const int csrc = (slot & 7) ^ (r & 7);
            gld_lds16((const char*)(tile0 + (size_t)wv * PSTP_) + (r * 8 + csrc) * 16,
                      (char*)&Sm[wv][part * 64]);
        }
    }

    u32x4 idf[2];
    {
        const int e = l16 & 7;
        const unsigned int bits = (e & 1) ? 0x3F800000u : 0x3F80u;
#pragma unroll
        for (int par = 0; par < 2; ++par) {
            u32x4 v = {};
            if (quad == (l16 >> 3) + par * 2) v[e >> 1] = bits;
            idf[par] = v;
        }
    }

    // rotated transpose-buffer accessors (row = 128 B, rot = 16*(row&7));
    // guarded variants return 0 for rows >= 52 (old pad region)
    auto twr = [&](unsigned short* buf, int rb, int colb, ull v) {
        if (rb < 52)
            *(ull_a*)((char*)buf + rb * 128 + ((colb + 16 * (rb & 7)) & 127)) = v;
    };
    auto trdg = [&](const unsigned short* buf, int r, int colb) -> u32x4 {
        u32x4 v = {};
        if (r < 52)
            v = *(const u32x4_a*)((char*)buf + r * 128 + ((colb + 16 * (r & 7)) & 127));
        return v;
    };
    auto smg = [&](const u32x4* S, int r, int idx) -> u32x4 {
        u32x4 v = {};
        if (r < 52) v = S[r * 8 + idx];
        return v;
    };
    const int wcol = wv * 32 + quad * 8;    // transposed-write byte col

    const int ra = wv * 16 + l16;
    const f32x4 z = {};
    asm volatile("s_waitcnt vmcnt(0)" ::: "memory");
    __syncthreads();

    // Phase A: Tb[0] = T1^T rows, Tb[1] = T3^T rows (identity MFMA)
#pragma unroll
    for (int tt = 0; tt < 2; ++tt) {
        const u32x4* S = Sm[tt * 2];
        bf16x8 a0 = as_bf16x8(smg(S, ra, quad ^ (ra & 7)));
        bf16x8 a1 = as_bf16x8(smg(S, ra, (4 + quad) ^ (ra & 7)));
#pragma unroll
        for (int nf = 0; nf < 4; ++nf) {
            f32x4 d = __builtin_amdgcn_mfma_f32_16x16x32_bf16(
                (nf >> 1) ? a1 : a0, as_bf16x8(idf[nf & 1]), z, 0, 0, 0);
            twr(Tb[tt], nf * 16 + l16, wcol, pack4(d));
        }
    }
    __syncthreads();

    // Phase B: W2 = T2·T1 (store W2^T rows -> Sm[0]); W4^T = T3^T·T4^T (-> Sm[2])
    {
        bf16x8 a2[2], a3[2];
#pragma unroll
        for (int ks = 0; ks < 2; ++ks) {
            a2[ks] = as_bf16x8(smg(Sm[1], ra, (ks * 4 + quad) ^ (ra & 7)));
            a3[ks] = as_bf16x8(trdg(Tb[1], ra, ks * 64 + quad * 16));
        }
        ull w2v[4], w4v[4];
#pragma unroll
        for (int nf = 0; nf < 4; ++nf) {
            const int rb = nf * 16 + l16;
            f32x4 u = z, v = z;
#pragma unroll
            for (int ks = 0; ks < 2; ++ks) {
                bf16x8 bU = as_bf16x8(trdg(Tb[0], rb, ks * 64 + quad * 16));
                bf16x8 bV = as_bf16x8(smg(Sm[3], rb, (ks * 4 + quad) ^ (rb & 7)));
                u = __builtin_amdgcn_mfma_f32_16x16x32_bf16(a2[ks], bU, u, 0, 0, 0);
                v = __builtin_amdgcn_mfma_f32_16x16x32_bf16(a3[ks], bV, v, 0, 0, 0);
            }
            w2v[nf] = pack4(u);
            w4v[nf] = pack4(v);
        }
        __syncthreads();   // Sm[0]/Sm[2] reads (phase A) done everywhere
#pragma unroll
        for (int nf = 0; nf < 4; ++nf) {
            twr(W2t, nf * 16 + l16, wcol, w2v[nf]);
            twr(W4b, nf * 16 + l16, wcol, w4v[nf]);
        }
    }
    __syncthreads();

    // Phase C: M rows -> Tb[0]
    {
        bf16x8 aw[2];
#pragma unroll
        for (int ks = 0; ks < 2; ++ks)
            aw[ks] = as_bf16x8(trdg(W2t, ra, ks * 64 + quad * 16));
        ull mv[4];
#pragma unroll
        for (int nf = 0; nf < 4; ++nf) {
            const int rb = nf * 16 + l16;
            f32x4 d = z;
#pragma unroll
            for (int ks = 0; ks < 2; ++ks) {
                bf16x8 bw = as_bf16x8(trdg(W4b, rb, ks * 64 + quad * 16));
                d = __builtin_amdgcn_mfma_f32_16x16x32_bf16(aw[ks], bw, d, 0, 0, 0);
            }
            mv[nf] = pack4(d);
        }
        __syncthreads();   // Tb[0] reads (phase B) done
#pragma unroll
        for (int nf = 0; nf < 4; ++nf)
            twr(Tb[0], nf * 16 + l16, wcol, mv[nf]);
    }
    __syncthreads();

    u32x4* qout = (u32x4*)(Q + (size_t)bq * PSTQ_);
#pragma unroll
    for (int c = tid; c < 512; c += 256) {
        const int row = c >> 3;
        const int pos = c & 7;
        qout[row * 8 + pos] = trdg(Tb[0], row, pos * 16);  // rows >=52 -> 0
    }
}

// ---------------------------------------------------------------------------
// scan_q: wave 0 = serial scan over quad-products; rescale every 2 steps via
// exponent extraction.  Round-7 version verbatim (validated absmax 0).
// ---------------------------------------------------------------------------
__global__ __launch_bounds__(128, 1) void scan_q(
    const __hip_bfloat16* __restrict__ Q,    // [B*Tq][PSTQ]
    const __hip_bfloat16* __restrict__ P,    // [B*Tc][PSTP]
    const int* __restrict__ target, const float* __restrict__ mask,
    float* __restrict__ p_ws, float* __restrict__ ls_ws,
    float* __restrict__ tgt_ws, float* __restrict__ out,
    int t0q, int Tq, int Tqtot)
{
    __shared__ __align__(16) unsigned short p_arr[64];
    __shared__ float tgt_sh;

    const int b    = blockIdx.x;
    const int tid  = threadIdx.x;
    const int wv   = tid >> 6;
    const int lane = tid & 63;
    const int quad = lane >> 4;
    const int l16  = lane & 15;
    const int t0 = t0q << 2, Tc = Tq << 2;

    float pv[4] = {0.f, 0.f, 0.f, 0.f};
    float logscale = 0.f;

    if (wv == 0) {
        if (t0q == 0) {
            p_arr[lane] = (lane == L_ - 1) ? (unsigned short)0x3F80 : (unsigned short)0;
        } else {
#pragma unroll
            for (int f = 0; f < 4; ++f) pv[f] = p_ws[b * 64 + f * 16 + l16];
            logscale = ls_ws[b];
            p_arr[quad * 16 + l16] = bf16bits(pv[quad]);
        }
        asm volatile("s_waitcnt lgkmcnt(0)" ::: "memory");

        int off[8];
#pragma unroll
        for (int f = 0; f < 4; ++f)
#pragma unroll
            for (int ks = 0; ks < 2; ++ks)
                off[f * 2 + ks] = (f * 16 + l16) * 8 + ks * 4 + quad;

        const u32x4* gp = (const u32x4*)Q + (size_t)b * Tq * (PSTQ_ / 8);
        const u32x4_a* pa = (const u32x4_a*)p_arr;

        u32x4 s0[8], s1[8], s2[8], s3[8];
        auto fetch = [&](u32x4 (&st)[8], int tl) {
            const u32x4* g = gp + (size_t)tl * (PSTQ_ / 8);
#pragma unroll
            for (int q = 0; q < 8; ++q) st[q] = g[off[q]];
        };
        fetch(s0, 0);
        if (1 < Tq) fetch(s1, 1);
        if (2 < Tq) fetch(s2, 2);
        if (3 < Tq) fetch(s3, 3);

        auto step = [&](u32x4 (&st)[8], int tl) {
            bf16x8 a0 = as_bf16x8(pa[quad]);
            bf16x8 a1 = as_bf16x8(pa[4 + quad]);
            const f32x4 z = {};
            f32x4 ae[4], ao[4];
#pragma unroll
            for (int f = 0; f < 4; ++f) {
                ae[f] = __builtin_amdgcn_mfma_f32_16x16x32_bf16(a0, as_bf16x8(st[f * 2 + 0]), z, 0, 0, 0);
                ao[f] = __builtin_amdgcn_mfma_f32_16x16x32_bf16(a1, as_bf16x8(st[f * 2 + 1]), z, 0, 0, 0);
            }
#pragma unroll
            for (int f = 0; f < 4; ++f) pv[f] = ae[f][0] + ao[f][0];

            if (((tl & 1) == 1) || (tl == Tq - 1)) {
                float mx = fmaxf(fmaxf(pv[0], pv[1]), fmaxf(pv[2], pv[3]));
                DPP_STEP(mx, fmaxf, 0xB1);
                DPP_STEP(mx, fmaxf, 0x4E);
                DPP_STEP(mx, fmaxf, 0x124);
                DPP_STEP(mx, fmaxf, 0x128);
                // exponent-only normalize: sc = 2^(127-e), ls += (e-127)*ln2
                const unsigned mb = __builtin_bit_cast(unsigned, mx);
                const int e = (int)((mb >> 23) & 0xFFu);
                const float sc =
                    __builtin_bit_cast(float, (unsigned)(254 - e) << 23);
                logscale += (float)(e - 127) * LN2_;
#pragma unroll
                for (int f = 0; f < 4; ++f) pv[f] *= sc;
            }
            p_arr[quad * 16 + l16] = bf16bits(pv[quad]);
            asm volatile("s_waitcnt lgkmcnt(0)" ::: "memory");
        };

        for (int tl = 0; tl < Tq; tl += 4) {
            step(s0, tl);
            if (tl + 4 < Tq) fetch(s0, tl + 4);
            if (tl + 1 < Tq) { step(s1, tl + 1); if (tl + 5 < Tq) fetch(s1, tl + 5); }
            if (tl + 2 < Tq) { step(s2, tl + 2); if (tl + 6 < Tq) fetch(s2, tl + 6); }
            if (tl + 3 < Tq) { step(s3, tl + 3); if (tl + 7 < Tq) fetch(s3, tl + 7); }
        }
    } else {
        // target-path gather
        float s = 0.f;
        for (int tl = lane; tl < Tc; tl += 64) {
            const int t = t0 + tl;
            const int j = target[b * T_ + t];
            const int i = (t == 0) ? (L_ - 1) : target[b * T_ + t - 1];
            const float m = (t == 0) ? 1.f : mask[b * T_ + t];
            if (m != 0.f) {
                const float pval =
                    __bfloat162float(P[(size_t)(b * Tc + tl) * PSTP_ + j * RS_ + i]);
                s += __logf(pval);
            }
        }
#pragma unroll
        for (int d = 1; d < 64; d <<= 1) s += __shfl_xor(s, d);
        if (lane == 0) {
            const float tot = (t0 == 0) ? s : tgt_ws[b] + s;
            tgt_ws[b] = tot;
            tgt_sh = tot;
        }
    }
    __syncthreads();

    if (wv == 0) {
        if (t0q + Tq == Tqtot) {
            float s = pv[0] + pv[1] + pv[2] + pv[3];
            DPP_STEP(s, addf, 0xB1);
            DPP_STEP(s, addf, 0x4E);
            DPP_STEP(s, addf, 0x124);
            DPP_STEP(s, addf, 0x128);
            if (lane == 0) out[b] = logscale + __logf(s) - tgt_sh;
        } else {
            if (quad == 0) {
#pragma unroll
                for (int f = 0; f < 4; ++f) p_ws[b * 64 + f * 16 + l16] = pv[f];
            }
            if (lane == 0) ls_ws[b] = logscale;
        }
    }
}

// ---------------------------------------------------------------------------
extern "C" void kernel_launch(void* const* d_in, const int* in_sizes, int n_in,
                              void* d_out, int out_size, void* d_ws, size_t ws_size,
                              hipStream_t stream)
{
    (void)in_sizes; (void)n_in; (void)out_size;
    const float* x       = (const float*)d_in[0];
    const float* mask    = (const float*)d_in[1];
    const int*   target  = (const int*)d_in[2];
    const float* state_W = (const float*)d_in[3];
    const float* state_b = (const float*)d_in[4];
    const float* trans_W = (const float*)d_in[5];
    const float* trans_b = (const float*)d_in[6];
    float* out = (float*)d_out;

    char* ws = (char*)d_ws;
    size_t off = 0;
    auto alloc = [&](size_t bytes) -> void* {
        void* p = ws + off;
        off = (off + bytes + 255) & ~(size_t)255;
        return p;
    };

    __hip_bfloat16* Wt   = (__hip_bfloat16*)alloc((size_t)NG_ * K_ * 2);
    float*          bias = (float*)alloc((size_t)NG_ * 4);
    __hip_bfloat16* xb   = (__hip_bfloat16*)alloc((size_t)B_ * T_ * K_ * 2);
    float*          p_ws = (float*)alloc((size_t)B_ * 64 * 4);
    float*          ls   = (float*)alloc((size_t)B_ * 4);
    float*          tgte = (float*)alloc((size_t)B_ * 4);
    const size_t fixed = off;

    int Tc = 256;
    while (Tc > 4 && fixed + (size_t)Tc * B_ * PSTP_ * 2
                   + (size_t)(Tc / 4) * B_ * PSTQ_ * 2 + 1024 > ws_size)
        Tc >>= 1;
    __hip_bfloat16* P = (__hip_bfloat16*)alloc((size_t)Tc * B_ * PSTP_ * 2);
    __hip_bfloat16* Q = (__hip_bfloat16*)alloc((size_t)(Tc / 4) * B_ * PSTQ_ * 2);
    int TcShift = 0;
    while ((1 << TcShift) < Tc) ++TcShift;

    prep_all<<<dim3(1088), 256, 0, stream>>>(
        trans_W, trans_b, state_W, state_b, x, Wt, bias, xb);

    for (int t0 = 0; t0 < T_; t0 += Tc) {
        const int mtiles = (B_ * Tc) / MT_;
        if (mtiles % 32 == 0) {
            // 4 m-quarter dispatches (identical total work): lowers top-5
            // visibility threshold to ~16 µs and measures per-dispatch gap.
            const int mq = mtiles / 4;           // 32 -> swz (%8==0) holds
            for (int q = 0; q < 4; ++q)
                gemm_energy<<<dim3((NG_ / NT_) * mq), 256, 0, stream>>>(
                    xb, Wt, bias, mask, P, t0, Tc, TcShift, 1, q * mq);
        } else {
            const int swz = (mtiles % 8 == 0) ? 1 : 0;
            gemm_energy<<<dim3((NG_ / NT_) * mtiles), 256, 0, stream>>>(
                xb, Wt, bias, mask, P, t0, Tc, TcShift, swz, 0);
        }
        prod_quad<<<dim3(B_ * (Tc / 4)), 256, 0, stream>>>(P, Q, Tc);
        scan_q<<<dim3(B_), 128, 0, stream>>>(Q, P, target, mask, p_ws, ls, tgte, out,
                                             t0 / 4, Tc / 4, T_ / 4);
    }
}

// Round 9
// 211.680 us; speedup vs baseline: 1.0155x; 1.0155x over previous
//
#include <hip/hip_runtime.h>
#include <hip/hip_bf16.h>

#define B_    64
#define T_    256
#define K_    256
#define L_    51
#define LL_   2601
#define RS_   64      // row stride inside one tile
#define NG_   3328    // GEMM N: 52*64 (j rows 0..51; row 51 zero)
#define PSTP_ 3328    // P tile stride per (b,t): 52 rows * 64 (pad rows dropped)
#define PSTQ_ 4096    // Q tile stride per quad group: 64 rows * 64
#define MT_   128
#define NT_   128
#define LOG2E_ 1.4426950408889634f
#define LN2_  0.6931471805599453f

typedef __bf16 bf16x8 __attribute__((ext_vector_type(8)));
typedef float  f32x4  __attribute__((ext_vector_type(4)));
typedef unsigned int u32x4 __attribute__((ext_vector_type(4)));
typedef u32x4 __attribute__((may_alias)) u32x4_a;
typedef unsigned long long ull;
typedef ull __attribute__((may_alias)) ull_a;
typedef unsigned short ushort_a __attribute__((may_alias));

static __device__ __forceinline__ bf16x8 as_bf16x8(u32x4 u) {
    return __builtin_bit_cast(bf16x8, u);
}
static __device__ __forceinline__ unsigned short bf16bits(float x) {
    return __builtin_bit_cast(unsigned short, __float2bfloat16(x));
}
static __device__ __forceinline__ ull pack4(f32x4 a) {
    return (ull)bf16bits(a[0]) | ((ull)bf16bits(a[1]) << 16) |
           ((ull)bf16bits(a[2]) << 32) | ((ull)bf16bits(a[3]) << 48);
}
static __device__ __forceinline__ void gld_lds16(const void* g, void* l) {
    __builtin_amdgcn_global_load_lds(
        (const __attribute__((address_space(1))) unsigned int*)g,
        (__attribute__((address_space(3))) unsigned int*)l, 16, 0, 0);
}

#define DPP_STEP(v, OP, CTRL)                                                   \
    {                                                                           \
        int _x = __builtin_bit_cast(int, v);                                    \
        float _o = __builtin_bit_cast(                                          \
            float, __builtin_amdgcn_update_dpp(_x, _x, CTRL, 0xF, 0xF, true));  \
        v = OP(v, _o);                                                          \
    }
static __device__ __forceinline__ float addf(float a, float b) { return a + b; }

// ---------------------------------------------------------------------------
// prep_all: blk [0,64)   -> Wt rows n=j*64+i for i=blk (LDS transpose) + bias,
//                           both pre-scaled by log2(e) (epilogue uses exp2)
//           blk [64,1088)-> x fp32 -> bf16
// ---------------------------------------------------------------------------
__global__ __launch_bounds__(256) void prep_all(
    const float* __restrict__ trans_W, const float* __restrict__ trans_b,
    const float* __restrict__ state_W, const float* __restrict__ state_b,
    const float* __restrict__ x,
    __hip_bfloat16* __restrict__ Wt, float* __restrict__ bias,
    __hip_bfloat16* __restrict__ xb)
{
    __shared__ __align__(16) __hip_bfloat16 Wl[52 * 258];
    const int blk = blockIdx.x, tid = threadIdx.x;

    if (blk < 64) {
        const int i = blk;
        if (i < L_) {
            const int jp = tid & 63, kk = tid >> 6;
            if (jp < 52) {
                for (int k = kk; k < K_; k += 4) {
                    float v = 0.f;
                    if (jp < L_) v = (trans_W[(size_t)k * LL_ + i * L_ + jp] +
                                      state_W[k * L_ + jp]) * LOG2E_;
                    Wl[jp * 258 + k] = __float2bfloat16(v);
                }
            }
            __syncthreads();
            for (int idx = tid; idx < 52 * 32; idx += 256) {
                const int j = idx >> 5, c = idx & 31;
                const unsigned int* row = (const unsigned int*)&Wl[j * 258];
                u32x4 v;
                v[0] = row[c * 4 + 0]; v[1] = row[c * 4 + 1];
                v[2] = row[c * 4 + 2]; v[3] = row[c * 4 + 3];
                *(u32x4*)(Wt + (size_t)((j << 6) + i) * K_ + c * 8) = v;
            }
        } else {
            const u32x4 z = {};
            for (int idx = tid; idx < 52 * 32; idx += 256) {
                const int j = idx >> 5, c = idx & 31;
                *(u32x4*)(Wt + (size_t)((j << 6) + i) * K_ + c * 8) = z;
            }
        }
        if (tid < 52) {
            const int j = tid;
            bias[(j << 6) + i] =
                (i < L_ && j < L_) ? (trans_b[i * L_ + j] + state_b[j]) * LOG2E_
                                   : 0.f;
        }
    } else {
        const int n4 = B_ * T_ * K_ / 4;
        const float4* x4 = (const float4*)x;
        ushort4* xb4 = (ushort4*)xb;
        for (int idx = (blk - 64) * 256 + tid; idx < n4; idx += 1024 * 256) {
            float4 v = x4[idx];
            ushort4 o;
            o.x = bf16bits(v.x); o.y = bf16bits(v.y);
            o.z = bf16bits(v.z); o.w = bf16bits(v.w);
            xb4[idx] = o;
        }
    }
}

// ---------------------------------------------------------------------------
// GEMM + exp epilogue.  Round-5/7 interior verbatim, single dispatch
// (round-8 quartering reverted: 208-block dispatches ran 1 block/CU with no
// inter-block overlap, +25 µs).  BK=32, 8 K-phases, double-buffered, 32 KB
// LDS, paired-row XOR swizzle (0 conflicts), counted vmcnt(4) + raw
// s_barrier, bias as MFMA C-init, exp2 epilogue, XCD remap.
// ---------------------------------------------------------------------------
__global__ __launch_bounds__(256) void gemm_energy(
    const __hip_bfloat16* __restrict__ xb,   // [B*T][K]
    const __hip_bfloat16* __restrict__ Wt,   // [NG][K]
    const float* __restrict__ bias,          // [NG] (pre-scaled by log2e)
    const float* __restrict__ mask,          // [B][T]
    __hip_bfloat16* __restrict__ P,          // [B*Tc][PSTP]
    int t0, int Tc, int TcShift, int swz)
{
    __shared__ __align__(16) char smem[32768];   // A dbuf 16K | B dbuf 16K

    const int tid  = threadIdx.x;
    const int lane = tid & 63;
    const int wv   = tid >> 6;
    const int quad = lane >> 4;
    const int l16  = lane & 15;

    int xt, yt;
    if (swz) {                       // id%8 -> XCD; m-tile yt == id (mod 8)
        const int r8 = blockIdx.x & 7;
        const int h  = blockIdx.x >> 3;
        const int qd = h / 26;
        xt = h - qd * 26;
        yt = r8 + 8 * qd;
    } else {
        const int qd = blockIdx.x / 26;
        xt = blockIdx.x - qd * 26;
        yt = qd;
    }
    const int m0 = yt * MT_;
    const int n0 = xt * NT_;
    const int mrow0 = (wv >> 1) * 64;
    const int ncol0 = (wv & 1) * 64;

    // early loads (issued before any staging so counted vmcnt stays valid)
    float bv[4];
#pragma unroll
    for (int nf = 0; nf < 4; ++nf) bv[nf] = bias[n0 + ncol0 + nf * 16 + l16];
    const int mrowg = m0 + mrow0 + lane;     // this lane's mask row
    const float mlane =
        mask[(mrowg >> TcShift) * T_ + t0 + (mrowg & (Tc - 1))];

    // staging: slot s=it*256+tid -> line=s>>3, phys=s&7; logical h=phys^(line&7)
    // -> tile row r=line*2+(h>>2), k-chunk c=h&3.  LDS dest stays linear.
    const char* asrc[2]; const char* bsrc[2]; char* adst[2]; char* bdst[2];
#pragma unroll
    for (int it = 0; it < 2; ++it) {
        const int s = it * 256 + tid;
        const int line = s >> 3, phys = s & 7;
        const int h = phys ^ (line & 7);
        const int r = line * 2 + (h >> 2);
        const int c = h & 3;
        const int ma = m0 + r;
        const int rg = (ma >> TcShift) * T_ + t0 + (ma & (Tc - 1));
        asrc[it] = (const char*)xb + (size_t)rg * 512 + c * 16;
        bsrc[it] = (const char*)Wt + (size_t)(n0 + r) * 512 + c * 16;
        adst[it] = smem + it * 4096 + wv * 1024;
        bdst[it] = smem + 16384 + it * 4096 + wv * 1024;
    }
    auto stage = [&](int kp, int bsel) {
        const int ko = kp * 64;
#pragma unroll
        for (int it = 0; it < 2; ++it) {
            gld_lds16(asrc[it] + ko, adst[it] + bsel * 8192);
            gld_lds16(bsrc[it] + ko, bdst[it] + bsel * 8192);
        }
    };

    stage(0, 0);

    f32x4 acc[4][4];                             // C-init = bias (scaled)
#pragma unroll
    for (int mf = 0; mf < 4; ++mf)
#pragma unroll
        for (int nf = 0; nf < 4; ++nf)
            acc[mf][nf] = (f32x4){bv[nf], bv[nf], bv[nf], bv[nf]};

#pragma unroll
    for (int kp = 0; kp < 8; ++kp) {
        if (kp < 7) {
            stage(kp + 1, (kp + 1) & 1);         // next phase, other buffer
            asm volatile("s_waitcnt vmcnt(4)" ::: "memory");  // phase kp done
        } else {
            asm volatile("s_waitcnt vmcnt(0)" ::: "memory");
        }
        __builtin_amdgcn_s_barrier();
        const u32x4_a* Av = (const u32x4_a*)(smem + (kp & 1) * 8192);
        const u32x4_a* Bv = (const u32x4_a*)(smem + 16384 + (kp & 1) * 8192);
        __builtin_amdgcn_s_setprio(1);
        bf16x8 af[4], bfr[4];
#pragma unroll
        for (int f = 0; f < 4; ++f) {
            const int ra = mrow0 + f * 16 + l16;
            const int ia = (ra >> 1) * 8 + ((((ra & 1) << 2) | quad) ^ ((ra >> 1) & 7));
            af[f]  = as_bf16x8(Av[ia]);
            const int rb = ncol0 + f * 16 + l16;
            const int ib = (rb >> 1) * 8 + ((((rb & 1) << 2) | quad) ^ ((rb >> 1) & 7));
            bfr[f] = as_bf16x8(Bv[ib]);
        }
#pragma unroll
        for (int mf = 0; mf < 4; ++mf)
#pragma unroll
            for (int nf = 0; nf < 4; ++nf)
                acc[mf][nf] = __builtin_amdgcn_mfma_f32_16x16x32_bf16(
                    af[mf], bfr[nf], acc[mf][nf], 0, 0, 0);
        __builtin_amdgcn_s_setprio(0);
        asm volatile("s_waitcnt lgkmcnt(0)" ::: "memory");  // reads landed
        if (kp < 7) __builtin_amdgcn_s_barrier();  // buffer safe to overwrite
    }
    __syncthreads();   // full fence before reusing smem as epilogue tile

    // ---- epilogue ----  E: 128 rows x 256 B, row ml rotated by 8*ml bytes
    char* E = smem;
    const int jcol = (n0 + ncol0) >> 6;          // wave-uniform tile row j
    const bool jok = jcol < L_;
    const bool fastw = __all(mlane == 1.f);      // wave-uniform unmasked path
    const int colb0 = (ncol0 + l16) * 2;

    if (!jok) {
#pragma unroll
        for (int mf = 0; mf < 4; ++mf)
#pragma unroll
            for (int r = 0; r < 4; ++r) {
                const int ml = mrow0 + mf * 16 + quad * 4 + r;
                char* erow = E + ml * 256;
                const int rot = (ml * 8) & 255;
#pragma unroll
                for (int nf = 0; nf < 4; ++nf)
                    *(ushort_a*)(erow + ((colb0 + nf * 32 + rot) & 255)) = 0;
            }
    } else if (fastw) {
        const bool ok3 = (l16 < 3);              // cols 48..50 valid at nf=3
#pragma unroll
        for (int mf = 0; mf < 4; ++mf)
#pragma unroll
            for (int r = 0; r < 4; ++r) {
                const int ml = mrow0 + mf * 16 + quad * 4 + r;
                char* erow = E + ml * 256;
                const int rot = (ml * 8) & 255;
#pragma unroll
                for (int nf = 0; nf < 4; ++nf) {
                    float v = __builtin_exp2f(acc[mf][nf][r]);
                    if (nf == 3) v = ok3 ? v : 0.f;
                    *(ushort_a*)(erow + ((colb0 + nf * 32 + rot) & 255)) =
                        bf16bits(v);
                }
            }
    } else {
#pragma unroll
        for (int mf = 0; mf < 4; ++mf)
#pragma unroll
            for (int r = 0; r < 4; ++r) {
                const int ml = mrow0 + mf * 16 + quad * 4 + r;
                const int t  = t0 + ((m0 + ml) & (Tc - 1));
                const float mval = __shfl(mlane, ml - mrow0);
                const bool idm = (mval == 0.f) && (t != 0);
                char* erow = E + ml * 256;
                const int rot = (ml * 8) & 255;
#pragma unroll
                for (int nf = 0; nf < 4; ++nf) {
                    const bool okn = (nf < 3) || (l16 < 3);
                    const int ii = nf * 16 + l16;
                    float v;
                    if (idm) v = (okn && ii == jcol) ? 1.f : 0.f;
                    else     v = okn ? __builtin_exp2f(acc[mf][nf][r] * mval) : 0.f;
                    *(ushort_a*)(erow + ((colb0 + nf * 32 + rot) & 255)) =
                        bf16bits(v);
                }
            }
    }
    __syncthreads();

    // Coalesced store: 16 lanes cover one row's 256 B contiguous
#pragma unroll
    for (int it2 = 0; it2 < 8; ++it2) {
        const int idx = it2 * 256 + tid;
        const int ml = idx >> 4, c = idx & 15;
        const char* erow = E + ml * 256;
        const int rot = (ml * 8) & 255;
        const ull lo = *(const ull_a*)(erow + ((c * 16 + rot) & 255));
        const ull hi = *(const ull_a*)(erow + ((c * 16 + 8 + rot) & 255));
        u32x4 v;
        v[0] = (unsigned int)lo; v[1] = (unsigned int)(lo >> 32);
        v[2] = (unsigned int)hi; v[3] = (unsigned int)(hi >> 32);
        *(u32x4*)(P + (size_t)(m0 + ml) * PSTP_ + n0 + c * 8) = v;
    }
}

// ---------------------------------------------------------------------------
// prod_quad: Q = T4·T3·T2·T1, all-MFMA pair tree.  Round-7 version verbatim
// (52-row LDS tiles, 39.9 KB, 4 blocks/CU; validated absmax 0).
// NOTE: pure function P -> Q; launched TWICE this round (second run writes
// identical bytes) purely to measure its duration via total-time delta.
// ---------------------------------------------------------------------------
__global__ __launch_bounds__(256) void prod_quad(
    const __hip_bfloat16* __restrict__ P,   // [B*Tc][PSTP]
    __hip_bfloat16* __restrict__ Q,         // [B*(Tc/4)][PSTQ]
    int Tc)
{
    __shared__ u32x4 Sm[4][416];                            // 4 x 52 rows = 26.6 KB
    __shared__ __align__(16) unsigned short Tb[2][52 * 64]; // 13.3 KB

    unsigned short* W2t = (unsigned short*)&Sm[0][0];       // 52-row overlay
    unsigned short* W4b = (unsigned short*)&Sm[2][0];

    const int tid  = threadIdx.x;
    const int wv   = tid >> 6;
    const int lane = tid & 63;
    const int quad = lane >> 4;
    const int l16  = lane & 15;
    const int bq = blockIdx.x;
    const int Tq = Tc >> 2;
    const int b  = bq / Tq;
    const int tq = bq - b * Tq;
    const __hip_bfloat16* tile0 = P + (size_t)(b * Tc + tq * 4) * PSTP_;

    // stage rows 0..51: wave wv owns tile wv, 7 parts (part 6 half-masked)
#pragma unroll
    for (int part = 0; part < 7; ++part) {
        const int slot = part * 64 + lane;
        const int r    = slot >> 3;
        if (r < 52) {
            const int csrc = (slot & 7) ^ (r & 7);
            gld_lds16((const char*)(tile0 + (size_t)wv * PSTP_) + (r * 8 + csrc) * 16,
                      (char*)&Sm[wv][part * 64]);
        }
    }

    u32x4 idf[2];
    {
        const int e = l16 & 7;
        const unsigned int bits = (e & 1) ? 0x3F800000u : 0x3F80u;
#pragma unroll
        for (int par = 0; par < 2; ++par) {
            u32x4 v = {};
            if (quad == (l16 >> 3) + par * 2) v[e >> 1] = bits;
            idf[par] = v;
        }
    }

    // rotated transpose-buffer accessors (row = 128 B, rot = 16*(row&7));
    // guarded variants return 0 for rows >= 52 (old pad region)
    auto twr = [&](unsigned short* buf, int rb, int colb, ull v) {
        if (rb < 52)
            *(ull_a*)((char*)buf + rb * 128 + ((colb + 16 * (rb & 7)) & 127)) = v;
    };
    auto trdg = [&](const unsigned short* buf, int r, int colb) -> u32x4 {
        u32x4 v = {};
        if (r < 52)
            v = *(const u32x4_a*)((char*)buf + r * 128 + ((colb + 16 * (r & 7)) & 127));
        return v;
    };
    auto smg = [&](const u32x4* S, int r, int idx) -> u32x4 {
        u32x4 v = {};
        if (r < 52) v = S[r * 8 + idx];
        return v;
    };
    const int wcol = wv * 32 + quad * 8;    // transposed-write byte col

    const int ra = wv * 16 + l16;
    const f32x4 z = {};
    asm volatile("s_waitcnt vmcnt(0)" ::: "memory");
    __syncthreads();

    // Phase A: Tb[0] = T1^T rows, Tb[1] = T3^T rows (identity MFMA)
#pragma unroll
    for (int tt = 0; tt < 2; ++tt) {
        const u32x4* S = Sm[tt * 2];
        bf16x8 a0 = as_bf16x8(smg(S, ra, quad ^ (ra & 7)));
        bf16x8 a1 = as_bf16x8(smg(S, ra, (4 + quad) ^ (ra & 7)));
#pragma unroll
        for (int nf = 0; nf < 4; ++nf) {
            f32x4 d = __builtin_amdgcn_mfma_f32_16x16x32_bf16(
                (nf >> 1) ? a1 : a0, as_bf16x8(idf[nf & 1]), z, 0, 0, 0);
            twr(Tb[tt], nf * 16 + l16, wcol, pack4(d));
        }
    }
    __syncthreads();

    // Phase B: W2 = T2·T1 (store W2^T rows -> Sm[0]); W4^T = T3^T·T4^T (-> Sm[2])
    {
        bf16x8 a2[2], a3[2];
#pragma unroll
        for (int ks = 0; ks < 2; ++ks) {
            a2[ks] = as_bf16x8(smg(Sm[1], ra, (ks * 4 + quad) ^ (ra & 7)));
            a3[ks] = as_bf16x8(trdg(Tb[1], ra, ks * 64 + quad * 16));
        }
        ull w2v[4], w4v[4];
#pragma unroll
        for (int nf = 0; nf < 4; ++nf) {
            const int rb = nf * 16 + l16;
            f32x4 u = z, v = z;
#pragma unroll
            for (int ks = 0; ks < 2; ++ks) {
                bf16x8 bU = as_bf16x8(trdg(Tb[0], rb, ks * 64 + quad * 16));
                bf16x8 bV = as_bf16x8(smg(Sm[3], rb, (ks * 4 + quad) ^ (rb & 7)));
                u = __builtin_amdgcn_mfma_f32_16x16x32_bf16(a2[ks], bU, u, 0, 0, 0);
                v = __builtin_amdgcn_mfma_f32_16x16x32_bf16(a3[ks], bV, v, 0, 0, 0);
            }
            w2v[nf] = pack4(u);
            w4v[nf] = pack4(v);
        }
        __syncthreads();   // Sm[0]/Sm[2] reads (phase A) done everywhere
#pragma unroll
        for (int nf = 0; nf < 4; ++nf) {
            twr(W2t, nf * 16 + l16, wcol, w2v[nf]);
            twr(W4b, nf * 16 + l16, wcol, w4v[nf]);
        }
    }
    __syncthreads();

    // Phase C: M rows -> Tb[0]
    {
        bf16x8 aw[2];
#pragma unroll
        for (int ks = 0; ks < 2; ++ks)
            aw[ks] = as_bf16x8(trdg(W2t, ra, ks * 64 + quad * 16));
        ull mv[4];
#pragma unroll
        for (int nf = 0; nf < 4; ++nf) {
            const int rb = nf * 16 + l16;
            f32x4 d = z;
#pragma unroll
            for (int ks = 0; ks < 2; ++ks) {
                bf16x8 bw = as_bf16x8(trdg(W4b, rb, ks * 64 + quad * 16));
                d = __builtin_amdgcn_mfma_f32_16x16x32_bf16(aw[ks], bw, d, 0, 0, 0);
            }
            mv[nf] = pack4(d);
        }
        __syncthreads();   // Tb[0] reads (phase B) done
#pragma unroll
        for (int nf = 0; nf < 4; ++nf)
            twr(Tb[0], nf * 16 + l16, wcol, mv[nf]);
    }
    __syncthreads();

    u32x4* qout = (u32x4*)(Q + (size_t)bq * PSTQ_);
#pragma unroll
    for (int c = tid; c < 512; c += 256) {
        const int row = c >> 3;
        const int pos = c & 7;
        qout[row * 8 + pos] = trdg(Tb[0], row, pos * 16);  // rows >=52 -> 0
    }
}

// ---------------------------------------------------------------------------
// scan_q: wave 0 = serial scan over quad-products; rescale every 2 steps via
// exponent extraction.  Round-7 version verbatim (validated absmax 0).
// ---------------------------------------------------------------------------
__global__ __launch_bounds__(128, 1) void scan_q(
    const __hip_bfloat16* __restrict__ Q,    // [B*Tq][PSTQ]
    const __hip_bfloat16* __restrict__ P,    // [B*Tc][PSTP]
    const int* __restrict__ target, const float* __restrict__ mask,
    float* __restrict__ p_ws, float* __restrict__ ls_ws,
    float* __restrict__ tgt_ws, float* __restrict__ out,
    int t0q, int Tq, int Tqtot)
{
    __shared__ __align__(16) unsigned short p_arr[64];
    __shared__ float tgt_sh;

    const int b    = blockIdx.x;
    const int tid  = threadIdx.x;
    const int wv   = tid >> 6;
    const int lane = tid & 63;
    const int quad = lane >> 4;
    const int l16  = lane & 15;
    const int t0 = t0q << 2, Tc = Tq << 2;

    float pv[4] = {0.f, 0.f, 0.f, 0.f};
    float logscale = 0.f;

    if (wv == 0) {
        if (t0q == 0) {
            p_arr[lane] = (lane == L_ - 1) ? (unsigned short)0x3F80 : (unsigned short)0;
        } else {
#pragma unroll
            for (int f = 0; f < 4; ++f) pv[f] = p_ws[b * 64 + f * 16 + l16];
            logscale = ls_ws[b];
            p_arr[quad * 16 + l16] = bf16bits(pv[quad]);
        }
        asm volatile("s_waitcnt lgkmcnt(0)" ::: "memory");

        int off[8];
#pragma unroll
        for (int f = 0; f < 4; ++f)
#pragma unroll
            for (int ks = 0; ks < 2; ++ks)
                off[f * 2 + ks] = (f * 16 + l16) * 8 + ks * 4 + quad;

        const u32x4* gp = (const u32x4*)Q + (size_t)b * Tq * (PSTQ_ / 8);
        const u32x4_a* pa = (const u32x4_a*)p_arr;

        u32x4 s0[8], s1[8], s2[8], s3[8];
        auto fetch = [&](u32x4 (&st)[8], int tl) {
            const u32x4* g = gp + (size_t)tl * (PSTQ_ / 8);
#pragma unroll
            for (int q = 0; q < 8; ++q) st[q] = g[off[q]];
        };
        fetch(s0, 0);
        if (1 < Tq) fetch(s1, 1);
        if (2 < Tq) fetch(s2, 2);
        if (3 < Tq) fetch(s3, 3);

        auto step = [&](u32x4 (&st)[8], int tl) {
            bf16x8 a0 = as_bf16x8(pa[quad]);
            bf16x8 a1 = as_bf16x8(pa[4 + quad]);
            const f32x4 z = {};
            f32x4 ae[4], ao[4];
#pragma unroll
            for (int f = 0; f < 4; ++f) {
                ae[f] = __builtin_amdgcn_mfma_f32_16x16x32_bf16(a0, as_bf16x8(st[f * 2 + 0]), z, 0, 0, 0);
                ao[f] = __builtin_amdgcn_mfma_f32_16x16x32_bf16(a1, as_bf16x8(st[f * 2 + 1]), z, 0, 0, 0);
            }
#pragma unroll
            for (int f = 0; f < 4; ++f) pv[f] = ae[f][0] + ao[f][0];

            if (((tl & 1) == 1) || (tl == Tq - 1)) {
                float mx = fmaxf(fmaxf(pv[0], pv[1]), fmaxf(pv[2], pv[3]));
                DPP_STEP(mx, fmaxf, 0xB1);
                DPP_STEP(mx, fmaxf, 0x4E);
                DPP_STEP(mx, fmaxf, 0x124);
                DPP_STEP(mx, fmaxf, 0x128);
                // exponent-only normalize: sc = 2^(127-e), ls += (e-127)*ln2
                const unsigned mb = __builtin_bit_cast(unsigned, mx);
                const int e = (int)((mb >> 23) & 0xFFu);
                const float sc =
                    __builtin_bit_cast(float, (unsigned)(254 - e) << 23);
                logscale += (float)(e - 127) * LN2_;
#pragma unroll
                for (int f = 0; f < 4; ++f) pv[f] *= sc;
            }
            p_arr[quad * 16 + l16] = bf16bits(pv[quad]);
            asm volatile("s_waitcnt lgkmcnt(0)" ::: "memory");
        };

        for (int tl = 0; tl < Tq; tl += 4) {
            step(s0, tl);
            if (tl + 4 < Tq) fetch(s0, tl + 4);
            if (tl + 1 < Tq) { step(s1, tl + 1); if (tl + 5 < Tq) fetch(s1, tl + 5); }
            if (tl + 2 < Tq) { step(s2, tl + 2); if (tl + 6 < Tq) fetch(s2, tl + 6); }
            if (tl + 3 < Tq) { step(s3, tl + 3); if (tl + 7 < Tq) fetch(s3, tl + 7); }
        }
    } else {
        // target-path gather
        float s = 0.f;
        for (int tl = lane; tl < Tc; tl += 64) {
            const int t = t0 + tl;
            const int j = target[b * T_ + t];
            const int i = (t == 0) ? (L_ - 1) : target[b * T_ + t - 1];
            const float m = (t == 0) ? 1.f : mask[b * T_ + t];
            if (m != 0.f) {
                const float pval =
                    __bfloat162float(P[(size_t)(b * Tc + tl) * PSTP_ + j * RS_ + i]);
                s += __logf(pval);
            }
        }
#pragma unroll
        for (int d = 1; d < 64; d <<= 1) s += __shfl_xor(s, d);
        if (lane == 0) {
            const float tot = (t0 == 0) ? s : tgt_ws[b] + s;
            tgt_ws[b] = tot;
            tgt_sh = tot;
        }
    }
    __syncthreads();

    if (wv == 0) {
        if (t0q + Tq == Tqtot) {
            float s = pv[0] + pv[1] + pv[2] + pv[3];
            DPP_STEP(s, addf, 0xB1);
            DPP_STEP(s, addf, 0x4E);
            DPP_STEP(s, addf, 0x124);
            DPP_STEP(s, addf, 0x128);
            if (lane == 0) out[b] = logscale + __logf(s) - tgt_sh;
        } else {
            if (quad == 0) {
#pragma unroll
                for (int f = 0; f < 4; ++f) p_ws[b * 64 + f * 16 + l16] = pv[f];
            }
            if (lane == 0) ls_ws[b] = logscale;
        }
    }
}

// ---------------------------------------------------------------------------
extern "C" void kernel_launch(void* const* d_in, const int* in_sizes, int n_in,
                              void* d_out, int out_size, void* d_ws, size_t ws_size,
                              hipStream_t stream)
{
    (void)in_sizes; (void)n_in; (void)out_size;
    const float* x       = (const float*)d_in[0];
    const float* mask    = (const float*)d_in[1];
    const int*   target  = (const int*)d_in[2];
    const float* state_W = (const float*)d_in[3];
    const float* state_b = (const float*)d_in[4];
    const float* trans_W = (const float*)d_in[5];
    const float* trans_b = (const float*)d_in[6];
    float* out = (float*)d_out;

    char* ws = (char*)d_ws;
    size_t off = 0;
    auto alloc = [&](size_t bytes) -> void* {
        void* p = ws + off;
        off = (off + bytes + 255) & ~(size_t)255;
        return p;
    };

    __hip_bfloat16* Wt   = (__hip_bfloat16*)alloc((size_t)NG_ * K_ * 2);
    float*          bias = (float*)alloc((size_t)NG_ * 4);
    __hip_bfloat16* xb   = (__hip_bfloat16*)alloc((size_t)B_ * T_ * K_ * 2);
    float*          p_ws = (float*)alloc((size_t)B_ * 64 * 4);
    float*          ls   = (float*)alloc((size_t)B_ * 4);
    float*          tgte = (float*)alloc((size_t)B_ * 4);
    const size_t fixed = off;

    int Tc = 256;
    while (Tc > 4 && fixed + (size_t)Tc * B_ * PSTP_ * 2
                   + (size_t)(Tc / 4) * B_ * PSTQ_ * 2 + 1024 > ws_size)
        Tc >>= 1;
    __hip_bfloat16* P = (__hip_bfloat16*)alloc((size_t)Tc * B_ * PSTP_ * 2);
    __hip_bfloat16* Q = (__hip_bfloat16*)alloc((size_t)(Tc / 4) * B_ * PSTQ_ * 2);
    int TcShift = 0;
    while ((1 << TcShift) < Tc) ++TcShift;

    prep_all<<<dim3(1088), 256, 0, stream>>>(
        trans_W, trans_b, state_W, state_b, x, Wt, bias, xb);

    for (int t0 = 0; t0 < T_; t0 += Tc) {
        const int mtiles = (B_ * Tc) / MT_;
        const int swz = (mtiles % 8 == 0) ? 1 : 0;
        gemm_energy<<<dim3((NG_ / NT_) * mtiles), 256, 0, stream>>>(
            xb, Wt, bias, mask, P, t0, Tc, TcShift, swz);
        // prod_quad launched TWICE: pure P->Q function (idempotent), the
        // duplicate measures prod's duration: prod = total - 190.3 - gap.
        prod_quad<<<dim3(B_ * (Tc / 4)), 256, 0, stream>>>(P, Q, Tc);
        prod_quad<<<dim3(B_ * (Tc / 4)), 256, 0, stream>>>(P, Q, Tc);
        scan_q<<<dim3(B_), 128, 0, stream>>>(Q, P, target, mask, p_ws, ls, tgte, out,
                                             t0 / 4, Tc / 4, T_ / 4);
    }
}

// Round 10
// 192.792 us; speedup vs baseline: 1.1150x; 1.0980x over previous
//
#include <hip/hip_runtime.h>
#include <hip/hip_bf16.h>

#define B_    64
#define T_    256
#define K_    256
#define L_    51
#define LL_   2601
#define RS_   64      // row stride inside one tile
#define NG_   3328    // GEMM N: 52*64 (j rows 0..51; row 51 zero)
#define PSTP_ 3328    // P tile stride per (b,t): 52 rows * 64 (pad rows dropped)
#define PSTQ_ 4096    // Q tile stride per quad group: 64 rows * 64
#define MT_   128
#define NT_   128
#define LOG2E_ 1.4426950408889634f
#define LN2_  0.6931471805599453f

typedef __bf16 bf16x8 __attribute__((ext_vector_type(8)));
typedef float  f32x4  __attribute__((ext_vector_type(4)));
typedef unsigned int u32x4 __attribute__((ext_vector_type(4)));
typedef u32x4 __attribute__((may_alias)) u32x4_a;
typedef unsigned long long ull;
typedef ull __attribute__((may_alias)) ull_a;
typedef unsigned short ushort_a __attribute__((may_alias));

static __device__ __forceinline__ bf16x8 as_bf16x8(u32x4 u) {
    return __builtin_bit_cast(bf16x8, u);
}
static __device__ __forceinline__ unsigned short bf16bits(float x) {
    return __builtin_bit_cast(unsigned short, __float2bfloat16(x));
}
static __device__ __forceinline__ ull pack4(f32x4 a) {
    return (ull)bf16bits(a[0]) | ((ull)bf16bits(a[1]) << 16) |
           ((ull)bf16bits(a[2]) << 32) | ((ull)bf16bits(a[3]) << 48);
}
static __device__ __forceinline__ void gld_lds16(const void* g, void* l) {
    __builtin_amdgcn_global_load_lds(
        (const __attribute__((address_space(1))) unsigned int*)g,
        (__attribute__((address_space(3))) unsigned int*)l, 16, 0, 0);
}

#define DPP_STEP(v, OP, CTRL)                                                   \
    {                                                                           \
        int _x = __builtin_bit_cast(int, v);                                    \
        float _o = __builtin_bit_cast(                                          \
            float, __builtin_amdgcn_update_dpp(_x, _x, CTRL, 0xF, 0xF, true));  \
        v = OP(v, _o);                                                          \
    }
static __device__ __forceinline__ float addf(float a, float b) { return a + b; }

// ---------------------------------------------------------------------------
// prep_all: blk [0,64)   -> Wt rows n=j*64+i for i=blk (LDS transpose) + bias,
//                           both pre-scaled by log2(e) (epilogue uses exp2)
//           blk [64,1088)-> x fp32 -> bf16
// ---------------------------------------------------------------------------
__global__ __launch_bounds__(256) void prep_all(
    const float* __restrict__ trans_W, const float* __restrict__ trans_b,
    const float* __restrict__ state_W, const float* __restrict__ state_b,
    const float* __restrict__ x,
    __hip_bfloat16* __restrict__ Wt, float* __restrict__ bias,
    __hip_bfloat16* __restrict__ xb)
{
    __shared__ __align__(16) __hip_bfloat16 Wl[52 * 258];
    const int blk = blockIdx.x, tid = threadIdx.x;

    if (blk < 64) {
        const int i = blk;
        if (i < L_) {
            const int jp = tid & 63, kk = tid >> 6;
            if (jp < 52) {
                for (int k = kk; k < K_; k += 4) {
                    float v = 0.f;
                    if (jp < L_) v = (trans_W[(size_t)k * LL_ + i * L_ + jp] +
                                      state_W[k * L_ + jp]) * LOG2E_;
                    Wl[jp * 258 + k] = __float2bfloat16(v);
                }
            }
            __syncthreads();
            for (int idx = tid; idx < 52 * 32; idx += 256) {
                const int j = idx >> 5, c = idx & 31;
                const unsigned int* row = (const unsigned int*)&Wl[j * 258];
                u32x4 v;
                v[0] = row[c * 4 + 0]; v[1] = row[c * 4 + 1];
                v[2] = row[c * 4 + 2]; v[3] = row[c * 4 + 3];
                *(u32x4*)(Wt + (size_t)((j << 6) + i) * K_ + c * 8) = v;
            }
        } else {
            const u32x4 z = {};
            for (int idx = tid; idx < 52 * 32; idx += 256) {
                const int j = idx >> 5, c = idx & 31;
                *(u32x4*)(Wt + (size_t)((j << 6) + i) * K_ + c * 8) = z;
            }
        }
        if (tid < 52) {
            const int j = tid;
            bias[(j << 6) + i] =
                (i < L_ && j < L_) ? (trans_b[i * L_ + j] + state_b[j]) * LOG2E_
                                   : 0.f;
        }
    } else {
        const int n4 = B_ * T_ * K_ / 4;
        const float4* x4 = (const float4*)x;
        ushort4* xb4 = (ushort4*)xb;
        for (int idx = (blk - 64) * 256 + tid; idx < n4; idx += 1024 * 256) {
            float4 v = x4[idx];
            ushort4 o;
            o.x = bf16bits(v.x); o.y = bf16bits(v.y);
            o.z = bf16bits(v.z); o.w = bf16bits(v.w);
            xb4[idx] = o;
        }
    }
}

// ---------------------------------------------------------------------------
// GEMM + exp epilogue.  BK=32, 8 K-phases, QUAD-buffered staging with ONE
// barrier per phase (8 barriers vs round-5's 15): with the barrier at phase
// top, wave skew <= 1 phase-body, and the furthest-ahead stage target is
// buf (kp+2)%4 -- never buf kp%4 that a trailing wave still reads.  64 KB
// LDS -> 2 blocks/CU (r1/r6 showed 2-3 blocks ~neutral here).  Paired-row
// XOR swizzle (0 conflicts), counted vmcnt(4), bias as MFMA C-init, exp2
// epilogue, XCD remap -- all unchanged from the validated round-5 interior.
// ---------------------------------------------------------------------------
__global__ __launch_bounds__(256) void gemm_energy(
    const __hip_bfloat16* __restrict__ xb,   // [B*T][K]
    const __hip_bfloat16* __restrict__ Wt,   // [NG][K]
    const float* __restrict__ bias,          // [NG] (pre-scaled by log2e)
    const float* __restrict__ mask,          // [B][T]
    __hip_bfloat16* __restrict__ P,          // [B*Tc][PSTP]
    int t0, int Tc, int TcShift, int swz)
{
    __shared__ __align__(16) char smem[65536];   // A bufs 0..3 @0; B bufs @32K

    const int tid  = threadIdx.x;
    const int lane = tid & 63;
    const int wv   = tid >> 6;
    const int quad = lane >> 4;
    const int l16  = lane & 15;

    int xt, yt;
    if (swz) {                       // id%8 -> XCD; m-tile yt == id (mod 8)
        const int r8 = blockIdx.x & 7;
        const int h  = blockIdx.x >> 3;
        const int qd = h / 26;
        xt = h - qd * 26;
        yt = r8 + 8 * qd;
    } else {
        const int qd = blockIdx.x / 26;
        xt = blockIdx.x - qd * 26;
        yt = qd;
    }
    const int m0 = yt * MT_;
    const int n0 = xt * NT_;
    const int mrow0 = (wv >> 1) * 64;
    const int ncol0 = (wv & 1) * 64;

    // early loads (issued before any staging so counted vmcnt stays valid)
    float bv[4];
#pragma unroll
    for (int nf = 0; nf < 4; ++nf) bv[nf] = bias[n0 + ncol0 + nf * 16 + l16];
    const int mrowg = m0 + mrow0 + lane;     // this lane's mask row
    const float mlane =
        mask[(mrowg >> TcShift) * T_ + t0 + (mrowg & (Tc - 1))];

    // staging: slot s=it*256+tid -> line=s>>3, phys=s&7; logical h=phys^(line&7)
    // -> tile row r=line*2+(h>>2), k-chunk c=h&3.  LDS dest stays linear.
    const char* asrc[2]; const char* bsrc[2]; char* adst[2]; char* bdst[2];
#pragma unroll
    for (int it = 0; it < 2; ++it) {
        const int s = it * 256 + tid;
        const int line = s >> 3, phys = s & 7;
        const int h = phys ^ (line & 7);
        const int r = line * 2 + (h >> 2);
        const int c = h & 3;
        const int ma = m0 + r;
        const int rg = (ma >> TcShift) * T_ + t0 + (ma & (Tc - 1));
        asrc[it] = (const char*)xb + (size_t)rg * 512 + c * 16;
        bsrc[it] = (const char*)Wt + (size_t)(n0 + r) * 512 + c * 16;
        adst[it] = smem + it * 4096 + wv * 1024;           // A buf0 base
        bdst[it] = smem + 32768 + it * 4096 + wv * 1024;   // B buf0 base
    }
    auto stage = [&](int kp, int bsel) {
        const int ko = kp * 64;
#pragma unroll
        for (int it = 0; it < 2; ++it) {
            gld_lds16(asrc[it] + ko, adst[it] + bsel * 8192);
            gld_lds16(bsrc[it] + ko, bdst[it] + bsel * 8192);
        }
    };

    stage(0, 0);

    f32x4 acc[4][4];                             // C-init = bias (scaled)
#pragma unroll
    for (int mf = 0; mf < 4; ++mf)
#pragma unroll
        for (int nf = 0; nf < 4; ++nf)
            acc[mf][nf] = (f32x4){bv[nf], bv[nf], bv[nf], bv[nf]};

#pragma unroll
    for (int kp = 0; kp < 8; ++kp) {
        if (kp < 7) {
            stage(kp + 1, (kp + 1) & 3);         // next phase into buf (kp+1)%4
            asm volatile("s_waitcnt vmcnt(4)" ::: "memory");  // phase kp landed
        } else {
            asm volatile("s_waitcnt vmcnt(0)" ::: "memory");
        }
        __builtin_amdgcn_s_barrier();            // single barrier per phase
        const u32x4_a* Av = (const u32x4_a*)(smem + (kp & 3) * 8192);
        const u32x4_a* Bv = (const u32x4_a*)(smem + 32768 + (kp & 3) * 8192);
        __builtin_amdgcn_s_setprio(1);
        bf16x8 af[4], bfr[4];
#pragma unroll
        for (int f = 0; f < 4; ++f) {
            const int ra = mrow0 + f * 16 + l16;
            const int ia = (ra >> 1) * 8 + ((((ra & 1) << 2) | quad) ^ ((ra >> 1) & 7));
            af[f]  = as_bf16x8(Av[ia]);
            const int rb = ncol0 + f * 16 + l16;
            const int ib = (rb >> 1) * 8 + ((((rb & 1) << 2) | quad) ^ ((rb >> 1) & 7));
            bfr[f] = as_bf16x8(Bv[ib]);
        }
#pragma unroll
        for (int mf = 0; mf < 4; ++mf)
#pragma unroll
            for (int nf = 0; nf < 4; ++nf)
                acc[mf][nf] = __builtin_amdgcn_mfma_f32_16x16x32_bf16(
                    af[mf], bfr[nf], acc[mf][nf], 0, 0, 0);
        __builtin_amdgcn_s_setprio(0);
        asm volatile("s_waitcnt lgkmcnt(0)" ::: "memory");  // reads landed
    }
    __syncthreads();   // full fence before reusing smem as epilogue tile

    // ---- epilogue ----  E: 128 rows x 256 B, row ml rotated by 8*ml bytes
    char* E = smem;
    const int jcol = (n0 + ncol0) >> 6;          // wave-uniform tile row j
    const bool jok = jcol < L_;
    const bool fastw = __all(mlane == 1.f);      // wave-uniform unmasked path
    const int colb0 = (ncol0 + l16) * 2;

    if (!jok) {
#pragma unroll
        for (int mf = 0; mf < 4; ++mf)
#pragma unroll
            for (int r = 0; r < 4; ++r) {
                const int ml = mrow0 + mf * 16 + quad * 4 + r;
                char* erow = E + ml * 256;
                const int rot = (ml * 8) & 255;
#pragma unroll
                for (int nf = 0; nf < 4; ++nf)
                    *(ushort_a*)(erow + ((colb0 + nf * 32 + rot) & 255)) = 0;
            }
    } else if (fastw) {
        const bool ok3 = (l16 < 3);              // cols 48..50 valid at nf=3
#pragma unroll
        for (int mf = 0; mf < 4; ++mf)
#pragma unroll
            for (int r = 0; r < 4; ++r) {
                const int ml = mrow0 + mf * 16 + quad * 4 + r;
                char* erow = E + ml * 256;
                const int rot = (ml * 8) & 255;
#pragma unroll
                for (int nf = 0; nf < 4; ++nf) {
                    float v = __builtin_exp2f(acc[mf][nf][r]);
                    if (nf == 3) v = ok3 ? v : 0.f;
                    *(ushort_a*)(erow + ((colb0 + nf * 32 + rot) & 255)) =
                        bf16bits(v);
                }
            }
    } else {
#pragma unroll
        for (int mf = 0; mf < 4; ++mf)
#pragma unroll
            for (int r = 0; r < 4; ++r) {
                const int ml = mrow0 + mf * 16 + quad * 4 + r;
                const int t  = t0 + ((m0 + ml) & (Tc - 1));
                const float mval = __shfl(mlane, ml - mrow0);
                const bool idm = (mval == 0.f) && (t != 0);
                char* erow = E + ml * 256;
                const int rot = (ml * 8) & 255;
#pragma unroll
                for (int nf = 0; nf < 4; ++nf) {
                    const bool okn = (nf < 3) || (l16 < 3);
                    const int ii = nf * 16 + l16;
                    float v;
                    if (idm) v = (okn && ii == jcol) ? 1.f : 0.f;
                    else     v = okn ? __builtin_exp2f(acc[mf][nf][r] * mval) : 0.f;
                    *(ushort_a*)(erow + ((colb0 + nf * 32 + rot) & 255)) =
                        bf16bits(v);
                }
            }
    }
    __syncthreads();

    // Coalesced store: 16 lanes cover one row's 256 B contiguous
#pragma unroll
    for (int it2 = 0; it2 < 8; ++it2) {
        const int idx = it2 * 256 + tid;
        const int ml = idx >> 4, c = idx & 15;
        const char* erow = E + ml * 256;
        const int rot = (ml * 8) & 255;
        const ull lo = *(const ull_a*)(erow + ((c * 16 + rot) & 255));
        const ull hi = *(const ull_a*)(erow + ((c * 16 + 8 + rot) & 255));
        u32x4 v;
        v[0] = (unsigned int)lo; v[1] = (unsigned int)(lo >> 32);
        v[2] = (unsigned int)hi; v[3] = (unsigned int)(hi >> 32);
        *(u32x4*)(P + (size_t)(m0 + ml) * PSTP_ + n0 + c * 8) = v;
    }
}

// ---------------------------------------------------------------------------
// prod_quad: Q = T4·T3·T2·T1, all-MFMA pair tree.  Round-7 version verbatim
// (52-row LDS tiles, 39.9 KB, 4 blocks/CU; validated absmax 0).  Measured
// ~20 us (round-9 duplicate-launch delta) ~= 87% of its 17.3 us HBM floor.
// ---------------------------------------------------------------------------
__global__ __launch_bounds__(256) void prod_quad(
    const __hip_bfloat16* __restrict__ P,   // [B*Tc][PSTP]
    __hip_bfloat16* __restrict__ Q,         // [B*(Tc/4)][PSTQ]
    int Tc)
{
    __shared__ u32x4 Sm[4][416];                            // 4 x 52 rows = 26.6 KB
    __shared__ __align__(16) unsigned short Tb[2][52 * 64]; // 13.3 KB

    unsigned short* W2t = (unsigned short*)&Sm[0][0];       // 52-row overlay
    unsigned short* W4b = (unsigned short*)&Sm[2][0];

    const int tid  = threadIdx.x;
    const int wv   = tid >> 6;
    const int lane = tid & 63;
    const int quad = lane >> 4;
    const int l16  = lane & 15;
    const int bq = blockIdx.x;
    const int Tq = Tc >> 2;
    const int b  = bq / Tq;
    const int tq = bq - b * Tq;
    const __hip_bfloat16* tile0 = P + (size_t)(b * Tc + tq * 4) * PSTP_;

    // stage rows 0..51: wave wv owns tile wv, 7 parts (part 6 half-masked)
#pragma unroll
    for (int part = 0; part < 7; ++part) {
        const int slot = part * 64 + lane;
        const int r    = slot >> 3;
        if (r < 52) {
            const int csrc = (slot & 7) ^ (r & 7);
            gld_lds16((const char*)(tile0 + (size_t)wv * PSTP_) + (r * 8 + csrc) * 16,
                      (char*)&Sm[wv][part * 64]);
        }
    }

    u32x4 idf[2];
    {
        const int e = l16 & 7;
        const unsigned int bits = (e & 1) ? 0x3F800000u : 0x3F80u;
#pragma unroll
        for (int par = 0; par < 2; ++par) {
            u32x4 v = {};
            if (quad == (l16 >> 3) + par * 2) v[e >> 1] = bits;
            idf[par] = v;
        }
    }

    // rotated transpose-buffer accessors (row = 128 B, rot = 16*(row&7));
    // guarded variants return 0 for rows >= 52 (old pad region)
    auto twr = [&](unsigned short* buf, int rb, int colb, ull v) {
        if (rb < 52)
            *(ull_a*)((char*)buf + rb * 128 + ((colb + 16 * (rb & 7)) & 127)) = v;
    };
    auto trdg = [&](const unsigned short* buf, int r, int colb) -> u32x4 {
        u32x4 v = {};
        if (r < 52)
            v = *(const u32x4_a*)((char*)buf + r * 128 + ((colb + 16 * (r & 7)) & 127));
        return v;
    };
    auto smg = [&](const u32x4* S, int r, int idx) -> u32x4 {
        u32x4 v = {};
        if (r < 52) v = S[r * 8 + idx];
        return v;
    };
    const int wcol = wv * 32 + quad * 8;    // transposed-write byte col

    const int ra = wv * 16 + l16;
    const f32x4 z = {};
    asm volatile("s_waitcnt vmcnt(0)" ::: "memory");
    __syncthreads();

    // Phase A: Tb[0] = T1^T rows, Tb[1] = T3^T rows (identity MFMA)
#pragma unroll
    for (int tt = 0; tt < 2; ++tt) {
        const u32x4* S = Sm[tt * 2];
        bf16x8 a0 = as_bf16x8(smg(S, ra, quad ^ (ra & 7)));
        bf16x8 a1 = as_bf16x8(smg(S, ra, (4 + quad) ^ (ra & 7)));
#pragma unroll
        for (int nf = 0; nf < 4; ++nf) {
            f32x4 d = __builtin_amdgcn_mfma_f32_16x16x32_bf16(
                (nf >> 1) ? a1 : a0, as_bf16x8(idf[nf & 1]), z, 0, 0, 0);
            twr(Tb[tt], nf * 16 + l16, wcol, pack4(d));
        }
    }
    __syncthreads();

    // Phase B: W2 = T2·T1 (store W2^T rows -> Sm[0]); W4^T = T3^T·T4^T (-> Sm[2])
    {
        bf16x8 a2[2], a3[2];
#pragma unroll
        for (int ks = 0; ks < 2; ++ks) {
            a2[ks] = as_bf16x8(smg(Sm[1], ra, (ks * 4 + quad) ^ (ra & 7)));
            a3[ks] = as_bf16x8(trdg(Tb[1], ra, ks * 64 + quad * 16));
        }
        ull w2v[4], w4v[4];
#pragma unroll
        for (int nf = 0; nf < 4; ++nf) {
            const int rb = nf * 16 + l16;
            f32x4 u = z, v = z;
#pragma unroll
            for (int ks = 0; ks < 2; ++ks) {
                bf16x8 bU = as_bf16x8(trdg(Tb[0], rb, ks * 64 + quad * 16));
                bf16x8 bV = as_bf16x8(smg(Sm[3], rb, (ks * 4 + quad) ^ (rb & 7)));
                u = __builtin_amdgcn_mfma_f32_16x16x32_bf16(a2[ks], bU, u, 0, 0, 0);
                v = __builtin_amdgcn_mfma_f32_16x16x32_bf16(a3[ks], bV, v, 0, 0, 0);
            }
            w2v[nf] = pack4(u);
            w4v[nf] = pack4(v);
        }
        __syncthreads();   // Sm[0]/Sm[2] reads (phase A) done everywhere
#pragma unroll
        for (int nf = 0; nf < 4; ++nf) {
            twr(W2t, nf * 16 + l16, wcol, w2v[nf]);
            twr(W4b, nf * 16 + l16, wcol, w4v[nf]);
        }
    }
    __syncthreads();

    // Phase C: M rows -> Tb[0]
    {
        bf16x8 aw[2];
#pragma unroll
        for (int ks = 0; ks < 2; ++ks)
            aw[ks] = as_bf16x8(trdg(W2t, ra, ks * 64 + quad * 16));
        ull mv[4];
#pragma unroll
        for (int nf = 0; nf < 4; ++nf) {
            const int rb = nf * 16 + l16;
            f32x4 d = z;
#pragma unroll
            for (int ks = 0; ks < 2; ++ks) {
                bf16x8 bw = as_bf16x8(trdg(W4b, rb, ks * 64 + quad * 16));
                d = __builtin_amdgcn_mfma_f32_16x16x32_bf16(aw[ks], bw, d, 0, 0, 0);
            }
            mv[nf] = pack4(d);
        }
        __syncthreads();   // Tb[0] reads (phase B) done
#pragma unroll
        for (int nf = 0; nf < 4; ++nf)
            twr(Tb[0], nf * 16 + l16, wcol, mv[nf]);
    }
    __syncthreads();

    u32x4* qout = (u32x4*)(Q + (size_t)bq * PSTQ_);
#pragma unroll
    for (int c = tid; c < 512; c += 256) {
        const int row = c >> 3;
        const int pos = c & 7;
        qout[row * 8 + pos] = trdg(Tb[0], row, pos * 16);  // rows >=52 -> 0
    }
}

// ---------------------------------------------------------------------------
// scan_q: wave 0 = serial scan over quad-products; rescale every 2 steps via
// exponent extraction.  Round-7 version verbatim (validated absmax 0).
// ---------------------------------------------------------------------------
__global__ __launch_bounds__(128, 1) void scan_q(
    const __hip_bfloat16* __restrict__ Q,    // [B*Tq][PSTQ]
    const __hip_bfloat16* __restrict__ P,    // [B*Tc][PSTP]
    const int* __restrict__ target, const float* __restrict__ mask,
    float* __restrict__ p_ws, float* __restrict__ ls_ws,
    float* __restrict__ tgt_ws, float* __restrict__ out,
    int t0q, int Tq, int Tqtot)
{
    __shared__ __align__(16) unsigned short p_arr[64];
    __shared__ float tgt_sh;

    const int b    = blockIdx.x;
    const int tid  = threadIdx.x;
    const int wv   = tid >> 6;
    const int lane = tid & 63;
    const int quad = lane >> 4;
    const int l16  = lane & 15;
    const int t0 = t0q << 2, Tc = Tq << 2;

    float pv[4] = {0.f, 0.f, 0.f, 0.f};
    float logscale = 0.f;

    if (wv == 0) {
        if (t0q == 0) {
            p_arr[lane] = (lane == L_ - 1) ? (unsigned short)0x3F80 : (unsigned short)0;
        } else {
#pragma unroll
            for (int f = 0; f < 4; ++f) pv[f] = p_ws[b * 64 + f * 16 + l16];
            logscale = ls_ws[b];
            p_arr[quad * 16 + l16] = bf16bits(pv[quad]);
        }
        asm volatile("s_waitcnt lgkmcnt(0)" ::: "memory");

        int off[8];
#pragma unroll
        for (int f = 0; f < 4; ++f)
#pragma unroll
            for (int ks = 0; ks < 2; ++ks)
                off[f * 2 + ks] = (f * 16 + l16) * 8 + ks * 4 + quad;

        const u32x4* gp = (const u32x4*)Q + (size_t)b * Tq * (PSTQ_ / 8);
        const u32x4_a* pa = (const u32x4_a*)p_arr;

        u32x4 s0[8], s1[8], s2[8], s3[8];
        auto fetch = [&](u32x4 (&st)[8], int tl) {
            const u32x4* g = gp + (size_t)tl * (PSTQ_ / 8);
#pragma unroll
            for (int q = 0; q < 8; ++q) st[q] = g[off[q]];
        };
        fetch(s0, 0);
        if (1 < Tq) fetch(s1, 1);
        if (2 < Tq) fetch(s2, 2);
        if (3 < Tq) fetch(s3, 3);

        auto step = [&](u32x4 (&st)[8], int tl) {
            bf16x8 a0 = as_bf16x8(pa[quad]);
            bf16x8 a1 = as_bf16x8(pa[4 + quad]);
            const f32x4 z = {};
            f32x4 ae[4], ao[4];
#pragma unroll
            for (int f = 0; f < 4; ++f) {
                ae[f] = __builtin_amdgcn_mfma_f32_16x16x32_bf16(a0, as_bf16x8(st[f * 2 + 0]), z, 0, 0, 0);
                ao[f] = __builtin_amdgcn_mfma_f32_16x16x32_bf16(a1, as_bf16x8(st[f * 2 + 1]), z, 0, 0, 0);
            }
#pragma unroll
            for (int f = 0; f < 4; ++f) pv[f] = ae[f][0] + ao[f][0];

            if (((tl & 1) == 1) || (tl == Tq - 1)) {
                float mx = fmaxf(fmaxf(pv[0], pv[1]), fmaxf(pv[2], pv[3]));
                DPP_STEP(mx, fmaxf, 0xB1);
                DPP_STEP(mx, fmaxf, 0x4E);
                DPP_STEP(mx, fmaxf, 0x124);
                DPP_STEP(mx, fmaxf, 0x128);
                // exponent-only normalize: sc = 2^(127-e), ls += (e-127)*ln2
                const unsigned mb = __builtin_bit_cast(unsigned, mx);
                const int e = (int)((mb >> 23) & 0xFFu);
                const float sc =
                    __builtin_bit_cast(float, (unsigned)(254 - e) << 23);
                logscale += (float)(e - 127) * LN2_;
#pragma unroll
                for (int f = 0; f < 4; ++f) pv[f] *= sc;
            }
            p_arr[quad * 16 + l16] = bf16bits(pv[quad]);
            asm volatile("s_waitcnt lgkmcnt(0)" ::: "memory");
        };

        for (int tl = 0; tl < Tq; tl += 4) {
            step(s0, tl);
            if (tl + 4 < Tq) fetch(s0, tl + 4);
            if (tl + 1 < Tq) { step(s1, tl + 1); if (tl + 5 < Tq) fetch(s1, tl + 5); }
            if (tl + 2 < Tq) { step(s2, tl + 2); if (tl + 6 < Tq) fetch(s2, tl + 6); }
            if (tl + 3 < Tq) { step(s3, tl + 3); if (tl + 7 < Tq) fetch(s3, tl + 7); }
        }
    } else {
        // target-path gather
        float s = 0.f;
        for (int tl = lane; tl < Tc; tl += 64) {
            const int t = t0 + tl;
            const int j = target[b * T_ + t];
            const int i = (t == 0) ? (L_ - 1) : target[b * T_ + t - 1];
            const float m = (t == 0) ? 1.f : mask[b * T_ + t];
            if (m != 0.f) {
                const float pval =
                    __bfloat162float(P[(size_t)(b * Tc + tl) * PSTP_ + j * RS_ + i]);
                s += __logf(pval);
            }
        }
#pragma unroll
        for (int d = 1; d < 64; d <<= 1) s += __shfl_xor(s, d);
        if (lane == 0) {
            const float tot = (t0 == 0) ? s : tgt_ws[b] + s;
            tgt_ws[b] = tot;
            tgt_sh = tot;
        }
    }
    __syncthreads();

    if (wv == 0) {
        if (t0q + Tq == Tqtot) {
            float s = pv[0] + pv[1] + pv[2] + pv[3];
            DPP_STEP(s, addf, 0xB1);
            DPP_STEP(s, addf, 0x4E);
            DPP_STEP(s, addf, 0x124);
            DPP_STEP(s, addf, 0x128);
            if (lane == 0) out[b] = logscale + __logf(s) - tgt_sh;
        } else {
            if (quad == 0) {
#pragma unroll
                for (int f = 0; f < 4; ++f) p_ws[b * 64 + f * 16 + l16] = pv[f];
            }
            if (lane == 0) ls_ws[b] = logscale;
        }
    }
}

// ---------------------------------------------------------------------------
extern "C" void kernel_launch(void* const* d_in, const int* in_sizes, int n_in,
                              void* d_out, int out_size, void* d_ws, size_t ws_size,
                              hipStream_t stream)
{
    (void)in_sizes; (void)n_in; (void)out_size;
    const float* x       = (const float*)d_in[0];
    const float* mask    = (const float*)d_in[1];
    const int*   target  = (const int*)d_in[2];
    const float* state_W = (const float*)d_in[3];
    const float* state_b = (const float*)d_in[4];
    const float* trans_W = (const float*)d_in[5];
    const float* trans_b = (const float*)d_in[6];
    float* out = (float*)d_out;

    char* ws = (char*)d_ws;
    size_t off = 0;
    auto alloc = [&](size_t bytes) -> void* {
        void* p = ws + off;
        off = (off + bytes + 255) & ~(size_t)255;
        return p;
    };

    __hip_bfloat16* Wt   = (__hip_bfloat16*)alloc((size_t)NG_ * K_ * 2);
    float*          bias = (float*)alloc((size_t)NG_ * 4);
    __hip_bfloat16* xb   = (__hip_bfloat16*)alloc((size_t)B_ * T_ * K_ * 2);
    float*          p_ws = (float*)alloc((size_t)B_ * 64 * 4);
    float*          ls   = (float*)alloc((size_t)B_ * 4);
    float*          tgte = (float*)alloc((size_t)B_ * 4);
    const size_t fixed = off;

    int Tc = 256;
    while (Tc > 4 && fixed + (size_t)Tc * B_ * PSTP_ * 2
                   + (size_t)(Tc / 4) * B_ * PSTQ_ * 2 + 1024 > ws_size)
        Tc >>= 1;
    __hip_bfloat16* P = (__hip_bfloat16*)alloc((size_t)Tc * B_ * PSTP_ * 2);
    __hip_bfloat16* Q = (__hip_bfloat16*)alloc((size_t)(Tc / 4) * B_ * PSTQ_ * 2);
    int TcShift = 0;
    while ((1 << TcShift) < Tc) ++TcShift;

    prep_all<<<dim3(1088), 256, 0, stream>>>(
        trans_W, trans_b, state_W, state_b, x, Wt, bias, xb);

    for (int t0 = 0; t0 < T_; t0 += Tc) {
        const int mtiles = (B_ * Tc) / MT_;
        const int swz = (mtiles % 8 == 0) ? 1 : 0;
        gemm_energy<<<dim3((NG_ / NT_) * mtiles), 256, 0, stream>>>(
            xb, Wt, bias, mask, P, t0, Tc, TcShift, swz);
        prod_quad<<<dim3(B_ * (Tc / 4)), 256, 0, stream>>>(P, Q, Tc);
        scan_q<<<dim3(B_), 128, 0, stream>>>(Q, P, target, mask, p_ws, ls, tgte, out,
                                             t0 / 4, Tc / 4, T_ / 4);
    }
}

// Round 11
// 189.484 us; speedup vs baseline: 1.1344x; 1.0175x over previous
//
#include <hip/hip_runtime.h>
#include <hip/hip_bf16.h>

#define B_    64
#define T_    256
#define K_    256
#define L_    51
#define LL_   2601
#define RS_   64      // row stride inside one tile
#define NG_   3328    // GEMM N: 52*64 (j rows 0..51; row 51 zero)
#define PSTP_ 3328    // P tile stride per (b,t): 52 rows * 64 (pad rows dropped)
#define PSTQ_ 4096    // Q tile stride per quad group: 64 rows * 64
#define MT_   128
#define NT_   128
#define LOG2E_ 1.4426950408889634f
#define LN2_  0.6931471805599453f

typedef __bf16 bf16x8 __attribute__((ext_vector_type(8)));
typedef float  f32x4  __attribute__((ext_vector_type(4)));
typedef unsigned int u32x4 __attribute__((ext_vector_type(4)));
typedef u32x4 __attribute__((may_alias)) u32x4_a;
typedef unsigned long long ull;
typedef ull __attribute__((may_alias)) ull_a;
typedef unsigned short ushort_a __attribute__((may_alias));
typedef f32x4 __attribute__((may_alias)) f32x4_a;

static __device__ __forceinline__ bf16x8 as_bf16x8(u32x4 u) {
    return __builtin_bit_cast(bf16x8, u);
}
static __device__ __forceinline__ unsigned short bf16bits(float x) {
    return __builtin_bit_cast(unsigned short, __float2bfloat16(x));
}
static __device__ __forceinline__ ull pack4(f32x4 a) {
    return (ull)bf16bits(a[0]) | ((ull)bf16bits(a[1]) << 16) |
           ((ull)bf16bits(a[2]) << 32) | ((ull)bf16bits(a[3]) << 48);
}
static __device__ __forceinline__ void gld_lds16(const void* g, void* l) {
    __builtin_amdgcn_global_load_lds(
        (const __attribute__((address_space(1))) unsigned int*)g,
        (__attribute__((address_space(3))) unsigned int*)l, 16, 0, 0);
}

#define DPP_STEP(v, OP, CTRL)                                                   \
    {                                                                           \
        int _x = __builtin_bit_cast(int, v);                                    \
        float _o = __builtin_bit_cast(                                          \
            float, __builtin_amdgcn_update_dpp(_x, _x, CTRL, 0xF, 0xF, true));  \
        v = OP(v, _o);                                                          \
    }
static __device__ __forceinline__ float addf(float a, float b) { return a + b; }

// ---------------------------------------------------------------------------
// prep_all: blk [0,64)   -> Wt rows n=j*64+i for i=blk (LDS transpose) + bias,
//                           both pre-scaled by log2(e) (epilogue uses exp2)
//           blk [64,1088)-> x fp32 -> bf16
// ---------------------------------------------------------------------------
__global__ __launch_bounds__(256) void prep_all(
    const float* __restrict__ trans_W, const float* __restrict__ trans_b,
    const float* __restrict__ state_W, const float* __restrict__ state_b,
    const float* __restrict__ x,
    __hip_bfloat16* __restrict__ Wt, float* __restrict__ bias,
    __hip_bfloat16* __restrict__ xb)
{
    __shared__ __align__(16) __hip_bfloat16 Wl[52 * 258];
    const int blk = blockIdx.x, tid = threadIdx.x;

    if (blk < 64) {
        const int i = blk;
        if (i < L_) {
            const int jp = tid & 63, kk = tid >> 6;
            if (jp < 52) {
                for (int k = kk; k < K_; k += 4) {
                    float v = 0.f;
                    if (jp < L_) v = (trans_W[(size_t)k * LL_ + i * L_ + jp] +
                                      state_W[k * L_ + jp]) * LOG2E_;
                    Wl[jp * 258 + k] = __float2bfloat16(v);
                }
            }
            __syncthreads();
            for (int idx = tid; idx < 52 * 32; idx += 256) {
                const int j = idx >> 5, c = idx & 31;
                const unsigned int* row = (const unsigned int*)&Wl[j * 258];
                u32x4 v;
                v[0] = row[c * 4 + 0]; v[1] = row[c * 4 + 1];
                v[2] = row[c * 4 + 2]; v[3] = row[c * 4 + 3];
                *(u32x4*)(Wt + (size_t)((j << 6) + i) * K_ + c * 8) = v;
            }
        } else {
            const u32x4 z = {};
            for (int idx = tid; idx < 52 * 32; idx += 256) {
                const int j = idx >> 5, c = idx & 31;
                *(u32x4*)(Wt + (size_t)((j << 6) + i) * K_ + c * 8) = z;
            }
        }
        if (tid < 52) {
            const int j = tid;
            bias[(j << 6) + i] =
                (i < L_ && j < L_) ? (trans_b[i * L_ + j] + state_b[j]) * LOG2E_
                                   : 0.f;
        }
    } else {
        const int n4 = B_ * T_ * K_ / 4;
        const float4* x4 = (const float4*)x;
        ushort4* xb4 = (ushort4*)xb;
        for (int idx = (blk - 64) * 256 + tid; idx < n4; idx += 1024 * 256) {
            float4 v = x4[idx];
            ushort4 o;
            o.x = bf16bits(v.x); o.y = bf16bits(v.y);
            o.z = bf16bits(v.z); o.w = bf16bits(v.w);
            xb4[idx] = o;
        }
    }
}

// ---------------------------------------------------------------------------
// GEMM + exp epilogue.  K-loop = validated round-5 structure (BK=32, 8
// phases, double-buffered 32 KB LDS, counted vmcnt(4), XOR swizzle, XCD
// remap) with MFMA operands SWAPPED: acc = mfma(bfr, af, acc).  Identical
// products; C-layout transposes so each lane's 4 regs are 4 CONSECUTIVE
// n-columns (n = nf*16 + quad*4 + r) at one m-row (m = mf*16 + l16).
// Epilogue: pack4 -> 16 x ds_write_b64 per thread (was 64 x ds_write_b16,
// 4x fewer LDS ops); bias C-init becomes an f32x4 vector load.
// ---------------------------------------------------------------------------
__global__ __launch_bounds__(256) void gemm_energy(
    const __hip_bfloat16* __restrict__ xb,   // [B*T][K]
    const __hip_bfloat16* __restrict__ Wt,   // [NG][K]
    const float* __restrict__ bias,          // [NG] (pre-scaled by log2e)
    const float* __restrict__ mask,          // [B][T]
    __hip_bfloat16* __restrict__ P,          // [B*Tc][PSTP]
    int t0, int Tc, int TcShift, int swz)
{
    __shared__ __align__(16) char smem[32768];   // A dbuf 16K | B dbuf 16K

    const int tid  = threadIdx.x;
    const int lane = tid & 63;
    const int wv   = tid >> 6;
    const int quad = lane >> 4;
    const int l16  = lane & 15;

    int xt, yt;
    if (swz) {                       // id%8 -> XCD; m-tile yt == id (mod 8)
        const int r8 = blockIdx.x & 7;
        const int h  = blockIdx.x >> 3;
        const int qd = h / 26;
        xt = h - qd * 26;
        yt = r8 + 8 * qd;
    } else {
        const int qd = blockIdx.x / 26;
        xt = blockIdx.x - qd * 26;
        yt = qd;
    }
    const int m0 = yt * MT_;
    const int n0 = xt * NT_;
    const int mrow0 = (wv >> 1) * 64;
    const int ncol0 = (wv & 1) * 64;

    // early loads (issued before any staging so counted vmcnt stays valid)
    f32x4 bias4[4];
#pragma unroll
    for (int nf = 0; nf < 4; ++nf)
        bias4[nf] = *(const f32x4_a*)&bias[n0 + ncol0 + nf * 16 + quad * 4];
    const int mrowg = m0 + mrow0 + lane;     // this lane's mask row
    const float mlane =
        mask[(mrowg >> TcShift) * T_ + t0 + (mrowg & (Tc - 1))];

    // staging: slot s=it*256+tid -> line=s>>3, phys=s&7; logical h=phys^(line&7)
    // -> tile row r=line*2+(h>>2), k-chunk c=h&3.  LDS dest stays linear.
    const char* asrc[2]; const char* bsrc[2]; char* adst[2]; char* bdst[2];
#pragma unroll
    for (int it = 0; it < 2; ++it) {
        const int s = it * 256 + tid;
        const int line = s >> 3, phys = s & 7;
        const int h = phys ^ (line & 7);
        const int r = line * 2 + (h >> 2);
        const int c = h & 3;
        const int ma = m0 + r;
        const int rg = (ma >> TcShift) * T_ + t0 + (ma & (Tc - 1));
        asrc[it] = (const char*)xb + (size_t)rg * 512 + c * 16;
        bsrc[it] = (const char*)Wt + (size_t)(n0 + r) * 512 + c * 16;
        adst[it] = smem + it * 4096 + wv * 1024;
        bdst[it] = smem + 16384 + it * 4096 + wv * 1024;
    }
    auto stage = [&](int kp, int bsel) {
        const int ko = kp * 64;
#pragma unroll
        for (int it = 0; it < 2; ++it) {
            gld_lds16(asrc[it] + ko, adst[it] + bsel * 8192);
            gld_lds16(bsrc[it] + ko, bdst[it] + bsel * 8192);
        }
    };

    stage(0, 0);

    f32x4 acc[4][4];                             // C-init = bias (scaled)
#pragma unroll
    for (int mf = 0; mf < 4; ++mf)
#pragma unroll
        for (int nf = 0; nf < 4; ++nf)
            acc[mf][nf] = bias4[nf];

#pragma unroll
    for (int kp = 0; kp < 8; ++kp) {
        if (kp < 7) {
            stage(kp + 1, (kp + 1) & 1);         // next phase, other buffer
            asm volatile("s_waitcnt vmcnt(4)" ::: "memory");  // phase kp done
        } else {
            asm volatile("s_waitcnt vmcnt(0)" ::: "memory");
        }
        __builtin_amdgcn_s_barrier();
        const u32x4_a* Av = (const u32x4_a*)(smem + (kp & 1) * 8192);
        const u32x4_a* Bv = (const u32x4_a*)(smem + 16384 + (kp & 1) * 8192);
        __builtin_amdgcn_s_setprio(1);
        bf16x8 af[4], bfr[4];
#pragma unroll
        for (int f = 0; f < 4; ++f) {
            const int ra = mrow0 + f * 16 + l16;
            const int ia = (ra >> 1) * 8 + ((((ra & 1) << 2) | quad) ^ ((ra >> 1) & 7));
            af[f]  = as_bf16x8(Av[ia]);
            const int rb = ncol0 + f * 16 + l16;
            const int ib = (rb >> 1) * 8 + ((((rb & 1) << 2) | quad) ^ ((rb >> 1) & 7));
            bfr[f] = as_bf16x8(Bv[ib]);
        }
#pragma unroll
        for (int mf = 0; mf < 4; ++mf)
#pragma unroll
            for (int nf = 0; nf < 4; ++nf)
                acc[mf][nf] = __builtin_amdgcn_mfma_f32_16x16x32_bf16(
                    bfr[nf], af[mf], acc[mf][nf], 0, 0, 0);   // SWAPPED
        __builtin_amdgcn_s_setprio(0);
        asm volatile("s_waitcnt lgkmcnt(0)" ::: "memory");  // reads landed
        if (kp < 7) __builtin_amdgcn_s_barrier();  // buffer safe to overwrite
    }
    __syncthreads();   // full fence before reusing smem as epilogue tile

    // ---- epilogue ----  E: 128 rows x 256 B, row ml rotated by 8*ml bytes.
    // Swapped C-layout: lane (quad,l16), reg r of acc[mf][nf] holds
    // P[m0+mrow0+mf*16+l16][n0+ncol0+nf*16+quad*4+r] -- 4 consecutive n
    // per reg quartet -> one 8B packed write per (mf,nf).
    char* E = smem;
    const int jcol = (n0 + ncol0) >> 6;          // wave-uniform tile row j
    const bool jok = jcol < L_;
    const bool fastw = __all(mlane == 1.f);      // wave-uniform unmasked path
    const int cbase = (ncol0 + quad * 4) * 2;    // byte col base (+ nf*32)

    if (!jok) {
#pragma unroll
        for (int mf = 0; mf < 4; ++mf) {
            const int ml = mrow0 + mf * 16 + l16;
            char* erow = E + ml * 256;
            const int rot = (ml * 8) & 255;
#pragma unroll
            for (int nf = 0; nf < 4; ++nf)
                *(ull_a*)(erow + ((cbase + nf * 32 + rot) & 255)) = 0ull;
        }
    } else if (fastw) {
#pragma unroll
        for (int mf = 0; mf < 4; ++mf) {
            const int ml = mrow0 + mf * 16 + l16;
            char* erow = E + ml * 256;
            const int rot = (ml * 8) & 255;
#pragma unroll
            for (int nf = 0; nf < 4; ++nf) {
                f32x4 v;
#pragma unroll
                for (int r = 0; r < 4; ++r) {
                    const int i = nf * 16 + quad * 4 + r;   // n-local i
                    v[r] = (i < L_) ? __builtin_exp2f(acc[mf][nf][r]) : 0.f;
                }
                *(ull_a*)(erow + ((cbase + nf * 32 + rot) & 255)) = pack4(v);
            }
        }
    } else {
#pragma unroll
        for (int mf = 0; mf < 4; ++mf) {
            const int ml = mrow0 + mf * 16 + l16;
            const int t  = t0 + ((m0 + ml) & (Tc - 1));
            const float mval = __shfl(mlane, mf * 16 + l16);
            const bool idm = (mval == 0.f) && (t != 0);
            char* erow = E + ml * 256;
            const int rot = (ml * 8) & 255;
#pragma unroll
            for (int nf = 0; nf < 4; ++nf) {
                f32x4 v;
#pragma unroll
                for (int r = 0; r < 4; ++r) {
                    const int i = nf * 16 + quad * 4 + r;
                    const bool okn = i < L_;
                    if (idm) v[r] = (okn && i == jcol) ? 1.f : 0.f;
                    else     v[r] = okn ? __builtin_exp2f(acc[mf][nf][r] * mval)
                                        : 0.f;
                }
                *(ull_a*)(erow + ((cbase + nf * 32 + rot) & 255)) = pack4(v);
            }
        }
    }
    __syncthreads();

    // Coalesced store: 16 lanes cover one row's 256 B contiguous
#pragma unroll
    for (int it2 = 0; it2 < 8; ++it2) {
        const int idx = it2 * 256 + tid;
        const int ml = idx >> 4, c = idx & 15;
        const char* erow = E + ml * 256;
        const int rot = (ml * 8) & 255;
        const ull lo = *(const ull_a*)(erow + ((c * 16 + rot) & 255));
        const ull hi = *(const ull_a*)(erow + ((c * 16 + 8 + rot) & 255));
        u32x4 v;
        v[0] = (unsigned int)lo; v[1] = (unsigned int)(lo >> 32);
        v[2] = (unsigned int)hi; v[3] = (unsigned int)(hi >> 32);
        *(u32x4*)(P + (size_t)(m0 + ml) * PSTP_ + n0 + c * 8) = v;
    }
}

// ---------------------------------------------------------------------------
// prod_quad: Q = T4·T3·T2·T1, all-MFMA pair tree.  Round-7 version verbatim
// (52-row LDS tiles, 39.9 KB, 4 blocks/CU; validated absmax 0).  Measured
// ~20 us (round-9 duplicate-launch delta) ~= 87% of its 17.3 us HBM floor.
// ---------------------------------------------------------------------------
__global__ __launch_bounds__(256) void prod_quad(
    const __hip_bfloat16* __restrict__ P,   // [B*Tc][PSTP]
    __hip_bfloat16* __restrict__ Q,         // [B*(Tc/4)][PSTQ]
    int Tc)
{
    __shared__ u32x4 Sm[4][416];                            // 4 x 52 rows = 26.6 KB
    __shared__ __align__(16) unsigned short Tb[2][52 * 64]; // 13.3 KB

    unsigned short* W2t = (unsigned short*)&Sm[0][0];       // 52-row overlay
    unsigned short* W4b = (unsigned short*)&Sm[2][0];

    const int tid  = threadIdx.x;
    const int wv   = tid >> 6;
    const int lane = tid & 63;
    const int quad = lane >> 4;
    const int l16  = lane & 15;
    const int bq = blockIdx.x;
    const int Tq = Tc >> 2;
    const int b  = bq / Tq;
    const int tq = bq - b * Tq;
    const __hip_bfloat16* tile0 = P + (size_t)(b * Tc + tq * 4) * PSTP_;

    // stage rows 0..51: wave wv owns tile wv, 7 parts (part 6 half-masked)
#pragma unroll
    for (int part = 0; part < 7; ++part) {
        const int slot = part * 64 + lane;
        const int r    = slot >> 3;
        if (r < 52) {
            const int csrc = (slot & 7) ^ (r & 7);
            gld_lds16((const char*)(tile0 + (size_t)wv * PSTP_) + (r * 8 + csrc) * 16,
                      (char*)&Sm[wv][part * 64]);
        }
    }

    u32x4 idf[2];
    {
        const int e = l16 & 7;
        const unsigned int bits = (e & 1) ? 0x3F800000u : 0x3F80u;
#pragma unroll
        for (int par = 0; par < 2; ++par) {
            u32x4 v = {};
            if (quad == (l16 >> 3) + par * 2) v[e >> 1] = bits;
            idf[par] = v;
        }
    }

    // rotated transpose-buffer accessors (row = 128 B, rot = 16*(row&7));
    // guarded variants return 0 for rows >= 52 (old pad region)
    auto twr = [&](unsigned short* buf, int rb, int colb, ull v) {
        if (rb < 52)
            *(ull_a*)((char*)buf + rb * 128 + ((colb + 16 * (rb & 7)) & 127)) = v;
    };
    auto trdg = [&](const unsigned short* buf, int r, int colb) -> u32x4 {
        u32x4 v = {};
        if (r < 52)
            v = *(const u32x4_a*)((char*)buf + r * 128 + ((colb + 16 * (r & 7)) & 127));
        return v;
    };
    auto smg = [&](const u32x4* S, int r, int idx) -> u32x4 {
        u32x4 v = {};
        if (r < 52) v = S[r * 8 + idx];
        return v;
    };
    const int wcol = wv * 32 + quad * 8;    // transposed-write byte col

    const int ra = wv * 16 + l16;
    const f32x4 z = {};
    asm volatile("s_waitcnt vmcnt(0)" ::: "memory");
    __syncthreads();

    // Phase A: Tb[0] = T1^T rows, Tb[1] = T3^T rows (identity MFMA)
#pragma unroll
    for (int tt = 0; tt < 2; ++tt) {
        const u32x4* S = Sm[tt * 2];
        bf16x8 a0 = as_bf16x8(smg(S, ra, quad ^ (ra & 7)));
        bf16x8 a1 = as_bf16x8(smg(S, ra, (4 + quad) ^ (ra & 7)));
#pragma unroll
        for (int nf = 0; nf < 4; ++nf) {
            f32x4 d = __builtin_amdgcn_mfma_f32_16x16x32_bf16(
                (nf >> 1) ? a1 : a0, as_bf16x8(idf[nf & 1]), z, 0, 0, 0);
            twr(Tb[tt], nf * 16 + l16, wcol, pack4(d));
        }
    }
    __syncthreads();

    // Phase B: W2 = T2·T1 (store W2^T rows -> Sm[0]); W4^T = T3^T·T4^T (-> Sm[2])
    {
        bf16x8 a2[2], a3[2];
#pragma unroll
        for (int ks = 0; ks < 2; ++ks) {
            a2[ks] = as_bf16x8(smg(Sm[1], ra, (ks * 4 + quad) ^ (ra & 7)));
            a3[ks] = as_bf16x8(trdg(Tb[1], ra, ks * 64 + quad * 16));
        }
        ull w2v[4], w4v[4];
#pragma unroll
        for (int nf = 0; nf < 4; ++nf) {
            const int rb = nf * 16 + l16;
            f32x4 u = z, v = z;
#pragma unroll
            for (int ks = 0; ks < 2; ++ks) {
                bf16x8 bU = as_bf16x8(trdg(Tb[0], rb, ks * 64 + quad * 16));
                bf16x8 bV = as_bf16x8(smg(Sm[3], rb, (ks * 4 + quad) ^ (rb & 7)));
                u = __builtin_amdgcn_mfma_f32_16x16x32_bf16(a2[ks], bU, u, 0, 0, 0);
                v = __builtin_amdgcn_mfma_f32_16x16x32_bf16(a3[ks], bV, v, 0, 0, 0);
            }
            w2v[nf] = pack4(u);
            w4v[nf] = pack4(v);
        }
        __syncthreads();   // Sm[0]/Sm[2] reads (phase A) done everywhere
#pragma unroll
        for (int nf = 0; nf < 4; ++nf) {
            twr(W2t, nf * 16 + l16, wcol, w2v[nf]);
            twr(W4b, nf * 16 + l16, wcol, w4v[nf]);
        }
    }
    __syncthreads();

    // Phase C: M rows -> Tb[0]
    {
        bf16x8 aw[2];
#pragma unroll
        for (int ks = 0; ks < 2; ++ks)
            aw[ks] = as_bf16x8(trdg(W2t, ra, ks * 64 + quad * 16));
        ull mv[4];
#pragma unroll
        for (int nf = 0; nf < 4; ++nf) {
            const int rb = nf * 16 + l16;
            f32x4 d = z;
#pragma unroll
            for (int ks = 0; ks < 2; ++ks) {
                bf16x8 bw = as_bf16x8(trdg(W4b, rb, ks * 64 + quad * 16));
                d = __builtin_amdgcn_mfma_f32_16x16x32_bf16(aw[ks], bw, d, 0, 0, 0);
            }
            mv[nf] = pack4(d);
        }
        __syncthreads();   // Tb[0] reads (phase B) done
#pragma unroll
        for (int nf = 0; nf < 4; ++nf)
            twr(Tb[0], nf * 16 + l16, wcol, mv[nf]);
    }
    __syncthreads();

    u32x4* qout = (u32x4*)(Q + (size_t)bq * PSTQ_);
#pragma unroll
    for (int c = tid; c < 512; c += 256) {
        const int row = c >> 3;
        const int pos = c & 7;
        qout[row * 8 + pos] = trdg(Tb[0], row, pos * 16);  // rows >=52 -> 0
    }
}

// ---------------------------------------------------------------------------
// scan_q: wave 0 = serial scan over quad-products; rescale every 2 steps via
// exponent extraction.  Round-7 version verbatim (validated absmax 0).
// ---------------------------------------------------------------------------
__global__ __launch_bounds__(128, 1) void scan_q(
    const __hip_bfloat16* __restrict__ Q,    // [B*Tq][PSTQ]
    const __hip_bfloat16* __restrict__ P,    // [B*Tc][PSTP]
    const int* __restrict__ target, const float* __restrict__ mask,
    float* __restrict__ p_ws, float* __restrict__ ls_ws,
    float* __restrict__ tgt_ws, float* __restrict__ out,
    int t0q, int Tq, int Tqtot)
{
    __shared__ __align__(16) unsigned short p_arr[64];
    __shared__ float tgt_sh;

    const int b    = blockIdx.x;
    const int tid  = threadIdx.x;
    const int wv   = tid >> 6;
    const int lane = tid & 63;
    const int quad = lane >> 4;
    const int l16  = lane & 15;
    const int t0 = t0q << 2, Tc = Tq << 2;

    float pv[4] = {0.f, 0.f, 0.f, 0.f};
    float logscale = 0.f;

    if (wv == 0) {
        if (t0q == 0) {
            p_arr[lane] = (lane == L_ - 1) ? (unsigned short)0x3F80 : (unsigned short)0;
        } else {
#pragma unroll
            for (int f = 0; f < 4; ++f) pv[f] = p_ws[b * 64 + f * 16 + l16];
            logscale = ls_ws[b];
            p_arr[quad * 16 + l16] = bf16bits(pv[quad]);
        }
        asm volatile("s_waitcnt lgkmcnt(0)" ::: "memory");

        int off[8];
#pragma unroll
        for (int f = 0; f < 4; ++f)
#pragma unroll
            for (int ks = 0; ks < 2; ++ks)
                off[f * 2 + ks] = (f * 16 + l16) * 8 + ks * 4 + quad;

        const u32x4* gp = (const u32x4*)Q + (size_t)b * Tq * (PSTQ_ / 8);
        const u32x4_a* pa = (const u32x4_a*)p_arr;

        u32x4 s0[8], s1[8], s2[8], s3[8];
        auto fetch = [&](u32x4 (&st)[8], int tl) {
            const u32x4* g = gp + (size_t)tl * (PSTQ_ / 8);
#pragma unroll
            for (int q = 0; q < 8; ++q) st[q] = g[off[q]];
        };
        fetch(s0, 0);
        if (1 < Tq) fetch(s1, 1);
        if (2 < Tq) fetch(s2, 2);
        if (3 < Tq) fetch(s3, 3);

        auto step = [&](u32x4 (&st)[8], int tl) {
            bf16x8 a0 = as_bf16x8(pa[quad]);
            bf16x8 a1 = as_bf16x8(pa[4 + quad]);
            const f32x4 z = {};
            f32x4 ae[4], ao[4];
#pragma unroll
            for (int f = 0; f < 4; ++f) {
                ae[f] = __builtin_amdgcn_mfma_f32_16x16x32_bf16(a0, as_bf16x8(st[f * 2 + 0]), z, 0, 0, 0);
                ao[f] = __builtin_amdgcn_mfma_f32_16x16x32_bf16(a1, as_bf16x8(st[f * 2 + 1]), z, 0, 0, 0);
            }
#pragma unroll
            for (int f = 0; f < 4; ++f) pv[f] = ae[f][0] + ao[f][0];

            if (((tl & 1) == 1) || (tl == Tq - 1)) {
                float mx = fmaxf(fmaxf(pv[0], pv[1]), fmaxf(pv[2], pv[3]));
                DPP_STEP(mx, fmaxf, 0xB1);
                DPP_STEP(mx, fmaxf, 0x4E);
                DPP_STEP(mx, fmaxf, 0x124);
                DPP_STEP(mx, fmaxf, 0x128);
                // exponent-only normalize: sc = 2^(127-e), ls += (e-127)*ln2
                const unsigned mb = __builtin_bit_cast(unsigned, mx);
                const int e = (int)((mb >> 23) & 0xFFu);
                const float sc =
                    __builtin_bit_cast(float, (unsigned)(254 - e) << 23);
                logscale += (float)(e - 127) * LN2_;
#pragma unroll
                for (int f = 0; f < 4; ++f) pv[f] *= sc;
            }
            p_arr[quad * 16 + l16] = bf16bits(pv[quad]);
            asm volatile("s_waitcnt lgkmcnt(0)" ::: "memory");
        };

        for (int tl = 0; tl < Tq; tl += 4) {
            step(s0, tl);
            if (tl + 4 < Tq) fetch(s0, tl + 4);
            if (tl + 1 < Tq) { step(s1, tl + 1); if (tl + 5 < Tq) fetch(s1, tl + 5); }
            if (tl + 2 < Tq) { step(s2, tl + 2); if (tl + 6 < Tq) fetch(s2, tl + 6); }
            if (tl + 3 < Tq) { step(s3, tl + 3); if (tl + 7 < Tq) fetch(s3, tl + 7); }
        }
    } else {
        // target-path gather
        float s = 0.f;
        for (int tl = lane; tl < Tc; tl += 64) {
            const int t = t0 + tl;
            const int j = target[b * T_ + t];
            const int i = (t == 0) ? (L_ - 1) : target[b * T_ + t - 1];
            const float m = (t == 0) ? 1.f : mask[b * T_ + t];
            if (m != 0.f) {
                const float pval =
                    __bfloat162float(P[(size_t)(b * Tc + tl) * PSTP_ + j * RS_ + i]);
                s += __logf(pval);
            }
        }
#pragma unroll
        for (int d = 1; d < 64; d <<= 1) s += __shfl_xor(s, d);
        if (lane == 0) {
            const float tot = (t0 == 0) ? s : tgt_ws[b] + s;
            tgt_ws[b] = tot;
            tgt_sh = tot;
        }
    }
    __syncthreads();

    if (wv == 0) {
        if (t0q + Tq == Tqtot) {
            float s = pv[0] + pv[1] + pv[2] + pv[3];
            DPP_STEP(s, addf, 0xB1);
            DPP_STEP(s, addf, 0x4E);
            DPP_STEP(s, addf, 0x124);
            DPP_STEP(s, addf, 0x128);
            if (lane == 0) out[b] = logscale + __logf(s) - tgt_sh;
        } else {
            if (quad == 0) {
#pragma unroll
                for (int f = 0; f < 4; ++f) p_ws[b * 64 + f * 16 + l16] = pv[f];
            }
            if (lane == 0) ls_ws[b] = logscale;
        }
    }
}

// ---------------------------------------------------------------------------
extern "C" void kernel_launch(void* const* d_in, const int* in_sizes, int n_in,
                              void* d_out, int out_size, void* d_ws, size_t ws_size,
                              hipStream_t stream)
{
    (void)in_sizes; (void)n_in; (void)out_size;
    const float* x       = (const float*)d_in[0];
    const float* mask    = (const float*)d_in[1];
    const int*   target  = (const int*)d_in[2];
    const float* state_W = (const float*)d_in[3];
    const float* state_b = (const float*)d_in[4];
    const float* trans_W = (const float*)d_in[5];
    const float* trans_b = (const float*)d_in[6];
    float* out = (float*)d_out;

    char* ws = (char*)d_ws;
    size_t off = 0;
    auto alloc = [&](size_t bytes) -> void* {
        void* p = ws + off;
        off = (off + bytes + 255) & ~(size_t)255;
        return p;
    };

    __hip_bfloat16* Wt   = (__hip_bfloat16*)alloc((size_t)NG_ * K_ * 2);
    float*          bias = (float*)alloc((size_t)NG_ * 4);
    __hip_bfloat16* xb   = (__hip_bfloat16*)alloc((size_t)B_ * T_ * K_ * 2);
    float*          p_ws = (float*)alloc((size_t)B_ * 64 * 4);
    float*          ls   = (float*)alloc((size_t)B_ * 4);
    float*          tgte = (float*)alloc((size_t)B_ * 4);
    const size_t fixed = off;

    int Tc = 256;
    while (Tc > 4 && fixed + (size_t)Tc * B_ * PSTP_ * 2
                   + (size_t)(Tc / 4) * B_ * PSTQ_ * 2 + 1024 > ws_size)
        Tc >>= 1;
    __hip_bfloat16* P = (__hip_bfloat16*)alloc((size_t)Tc * B_ * PSTP_ * 2);
    __hip_bfloat16* Q = (__hip_bfloat16*)alloc((size_t)(Tc / 4) * B_ * PSTQ_ * 2);
    int TcShift = 0;
    while ((1 << TcShift) < Tc) ++TcShift;

    prep_all<<<dim3(1088), 256, 0, stream>>>(
        trans_W, trans_b, state_W, state_b, x, Wt, bias, xb);

    for (int t0 = 0; t0 < T_; t0 += Tc) {
        const int mtiles = (B_ * Tc) / MT_;
        const int swz = (mtiles % 8 == 0) ? 1 : 0;
        gemm_energy<<<dim3((NG_ / NT_) * mtiles), 256, 0, stream>>>(
            xb, Wt, bias, mask, P, t0, Tc, TcShift, swz);
        prod_quad<<<dim3(B_ * (Tc / 4)), 256, 0, stream>>>(P, Q, Tc);
        scan_q<<<dim3(B_), 128, 0, stream>>>(Q, P, target, mask, p_ws, ls, tgte, out,
                                             t0 / 4, Tc / 4, T_ / 4);
    }
}